// Round 11
// baseline (213.950 us; speedup 1.0000x reference)
//
#include <hip/hip_runtime.h>
#include <hip/hip_bf16.h>
#include <math.h>

// Problem constants
#define BATCH 2
#define SEQ   2048
#define DMODEL 1024
#define NHEADS 16
#define DHEAD 64
#define MROWS (BATCH*SEQ)   // 4096

typedef __attribute__((ext_vector_type(8))) short bf16x8;
typedef __attribute__((ext_vector_type(4))) short bf16x4;
typedef __attribute__((ext_vector_type(4))) float f32x4;

__device__ __forceinline__ short f2bf(float f) {   // RNE float->bf16
    union { float f; unsigned u; } c; c.f = f;
    unsigned r = (c.u + 0x7fffu + ((c.u >> 16) & 1u)) >> 16;
    return (short)r;
}

__device__ __forceinline__ void async_ld16(const void* g, void* l) {
    __builtin_amdgcn_global_load_lds(
        (const __attribute__((address_space(1))) unsigned*)g,
        (__attribute__((address_space(3))) unsigned*)l, 16, 0, 0);
}

// ---------------- fused prep: convert x -> bf16 AND transpose 4 weights ----------------
// blocks [0,2048): convert 8 elems/thread; blocks [2048,3072): weight transpose
__global__ __launch_bounds__(256) void prep(
    const float* __restrict__ x, short* __restrict__ xhi,
    const float* __restrict__ W0, const float* __restrict__ W1,
    const float* __restrict__ W2, const float* __restrict__ W3,
    short* __restrict__ oqkv, short* __restrict__ oo)
{
    __shared__ float T[64][65];
    const int tid = threadIdx.x;
    if (blockIdx.x < 2048) {
        const int i = blockIdx.x * 256 + tid;
        const float4* p = (const float4*)x + (size_t)i * 2;
        float4 a = p[0], b = p[1];
        float v[8] = {a.x, a.y, a.z, a.w, b.x, b.y, b.z, b.w};
        bf16x8 H;
        #pragma unroll
        for (int j = 0; j < 8; ++j) H[j] = f2bf(v[j]);
        *((bf16x8*)xhi + i) = H;
        return;
    }
    const int bi = blockIdx.x - 2048;
    const int z = bi >> 8;                 // matrix 0..3
    const int t = bi & 255;
    const float* W = (z == 0) ? W0 : (z == 1) ? W1 : (z == 2) ? W2 : W3;
    short* out = (z < 3) ? (oqkv + (size_t)z * 1024 * 1024) : oo;
    const int n0 = (t & 15) * 64, k0 = (t >> 4) * 64;
    #pragma unroll
    for (int i = 0; i < 16; ++i) {
        const int idx = tid + i * 256;
        const int r = idx >> 6, c = idx & 63;
        T[r][c] = W[(size_t)(k0 + r) * DMODEL + n0 + c];
    }
    __syncthreads();
    #pragma unroll
    for (int i = 0; i < 4; ++i) {
        const int idx = tid + i * 256;
        const int r = idx >> 4, g = idx & 15;
        bf16x4 H;
        #pragma unroll
        for (int j = 0; j < 4; ++j)
            H[j] = f2bf(T[g * 4 + j][r]);
        *(bf16x4*)(out + (size_t)(n0 + r) * DMODEL + k0 + g * 4) = H;
    }
}

// ---------------- MFMA GEMM: C = A[M,K] * Bt[N,K]^T, 1-term bf16 ----------------
// mode 0: q/k bf16 [B,H,S,64], v bf16 transposed [B,H,64,S] — stores routed
//         through per-wave LDS scratch (aliased on Ah/Bh) for coalesced b128.
// mode 1: row-major fp32 [M,1024] + bias
#define GBK 64

__global__ __launch_bounds__(256) void mfma_gemm(
    const short* __restrict__ Ahi, const short* __restrict__ Bthi,
    const float* __restrict__ b0, const float* __restrict__ b1, const float* __restrict__ b2,
    short* __restrict__ oqh, short* __restrict__ okh, short* __restrict__ ovh,
    float* __restrict__ outf, int mode, float qscale)
{
    __shared__ short Ah[128 * GBK], Bh[128 * GBK];   // 16 KB each

    const int tid  = threadIdx.x;
    const int lane = tid & 63;
    const int w    = tid >> 6;
    const int quad = lane >> 4;
    const int l15  = lane & 15;
    const int wr   = w >> 1, wc = w & 1;
    const int m0   = blockIdx.y * 128;
    const int n0   = blockIdx.x * 128;
    const int K    = DMODEL;

    f32x4 acc[4][4] = {};

    int srow[4], spos[4];
    #pragma unroll
    for (int j = 0; j < 4; ++j) {
        const int c = w * 256 + j * 64 + lane;
        srow[j] = c >> 3;
        spos[j] = (c & 7) ^ (srow[j] & 7);
    }

    for (int k0 = 0; k0 < K; k0 += GBK) {
        __syncthreads();
        #pragma unroll
        for (int j = 0; j < 4; ++j) {
            const int cB = (w * 256 + j * 64) * 8;
            async_ld16(Ahi + (size_t)(m0 + srow[j]) * K + k0 + spos[j] * 8, Ah + cB);
            async_ld16(Bthi + (size_t)(n0 + srow[j]) * K + k0 + spos[j] * 8, Bh + cB);
        }
        __syncthreads();

        #pragma unroll
        for (int s = 0; s < 2; ++s) {
            bf16x8 afh[4], bfh[4];
            #pragma unroll
            for (int mi = 0; mi < 4; ++mi) {
                const int row = wr * 64 + mi * 16 + l15;
                const int pos = (s * 4 + quad) ^ (row & 7);
                afh[mi] = *(const bf16x8*)(Ah + row * GBK + pos * 8);
            }
            #pragma unroll
            for (int ni = 0; ni < 4; ++ni) {
                const int row = wc * 64 + ni * 16 + l15;
                const int pos = (s * 4 + quad) ^ (row & 7);
                bfh[ni] = *(const bf16x8*)(Bh + row * GBK + pos * 8);
            }
            #pragma unroll
            for (int mi = 0; mi < 4; ++mi)
                #pragma unroll
                for (int ni = 0; ni < 4; ++ni)
                    acc[mi][ni] = __builtin_amdgcn_mfma_f32_16x16x32_bf16(
                        afh[mi], bfh[ni], acc[mi][ni], 0, 0, 0);
        }
    }

    const int nbase = n0 + wc * 64;
    if (mode == 1) {
        #pragma unroll
        for (int mi = 0; mi < 4; ++mi)
            #pragma unroll
            for (int ni = 0; ni < 4; ++ni)
                #pragma unroll
                for (int r = 0; r < 4; ++r) {
                    const int m = m0 + wr * 64 + mi * 16 + quad * 4 + r;
                    const int nn = nbase + ni * 16 + l15;
                    outf[(size_t)m * DMODEL + nn] = acc[mi][ni][r] + b0[nn];
                }
    } else {
        __syncthreads();   // all waves done reading Ah/Bh; reuse as scratch
        short* scr = (w < 2) ? (Ah + w * 4096) : (Bh + (w - 2) * 4096);  // 8 KB/wave
        const int which = nbase >> 10;               // 0=q, 1=k, 2=v (wave-uniform)
        const int hh = (nbase & 1023) >> 6;          // head (n-range = one head)
        const int mb = m0 + wr * 64;
        const int b = mb >> 11, sbase = mb & (SEQ - 1);

        if (which < 2) {
            const float* bias = which ? b1 : b0;
            short* dstp = which ? okh : oqh;
            const float scl = which ? 1.0f : qscale;
            #pragma unroll
            for (int mi = 0; mi < 4; ++mi)
                #pragma unroll
                for (int ni = 0; ni < 4; ++ni)
                    #pragma unroll
                    for (int r = 0; r < 4; ++r) {
                        const int sloc = mi * 16 + quad * 4 + r;
                        const int dloc = ni * 16 + l15;
                        const int nn = (nbase + ni * 16 + l15) & 1023;
                        scr[sloc * 64 + (((dloc >> 3) ^ (sloc & 7)) * 8) + (dloc & 7)] =
                            f2bf((acc[mi][ni][r] + bias[nn]) * scl);
                    }
            #pragma unroll
            for (int i = 0; i < 8; ++i) {
                const int sloc = i * 8 + (lane >> 3);
                const int cph = (lane & 7) ^ (sloc & 7);
                bf16x8 row = *(const bf16x8*)(scr + sloc * 64 + cph * 8);
                const int dloc = (lane & 7) * 8;
                *(bf16x8*)(dstp + ((size_t)(b * NHEADS + hh) * SEQ + sbase + sloc) * DHEAD + dloc) = row;
            }
        } else {
            #pragma unroll
            for (int mi = 0; mi < 4; ++mi)
                #pragma unroll
                for (int ni = 0; ni < 4; ++ni)
                    #pragma unroll
                    for (int r = 0; r < 4; ++r) {
                        const int sloc = mi * 16 + quad * 4 + r;
                        const int dloc = ni * 16 + l15;
                        const int nn = (nbase + ni * 16 + l15) & 1023;
                        scr[dloc * 64 + (((sloc >> 3) ^ (dloc & 7)) * 8) + (sloc & 7)] =
                            f2bf(acc[mi][ni][r] + b2[nn]);
                    }
            #pragma unroll
            for (int i = 0; i < 8; ++i) {
                const int dloc = i * 8 + (lane >> 3);
                const int cph = (lane & 7) ^ (dloc & 7);
                bf16x8 row = *(const bf16x8*)(scr + dloc * 64 + cph * 8);
                const int sg = sbase + (lane & 7) * 8;
                *(bf16x8*)(ovh + ((size_t)(b * NHEADS + hh) * DHEAD + dloc) * SEQ + sg) = row;
            }
        }
    }
}

// ---------------- MFMA flash attention v9: split-K x2 ----------------
// Each block: 128 q, HALF the keys (16 iters). Grid 1024 -> 3 blocks/CU
// resident (was 2). Writes unnormalized fp32 O_partial + fp32 l_partial;
// combine_o normalizes. blk&31 = bh keeps K/V XCD-local.
#define PP 72

__global__ __launch_bounds__(256) void attn_mfma(
    const short* __restrict__ Qh_g, const short* __restrict__ Kh_g,
    const short* __restrict__ Vth_g,
    float* __restrict__ op0, float* __restrict__ op1,
    float* __restrict__ l0g, float* __restrict__ l1g)
{
    __shared__ short Ksh[2][4096];       // [buf][key*64+d swizzled]
    __shared__ short Vsh[2][4096];       // [buf][d*64+s swizzled]
    __shared__ short Ph[4][2][16 * PP];  // per-wave, per-qfrag P tiles

    const int tid  = threadIdx.x;
    const int lane = tid & 63;
    const int w    = tid >> 6;
    const int quad = lane >> 4;
    const int l15  = lane & 15;

    const int bh    = blockIdx.x & 31;        // XCD-local head
    const int sk    = (blockIdx.x >> 5) & 1;  // K-split half
    const int qtile = blockIdx.x >> 6;        // 0..15
    const int q0    = qtile * 128 + w * 32;
    const size_t kvb = (size_t)bh * SEQ * DHEAD;

    bf16x8 ones;
    #pragma unroll
    for (int j = 0; j < 8; ++j) ones[j] = (short)0x3f80;   // bf16 1.0

    bf16x8 qA[2], qB[2];
    {
        const size_t qrA = kvb + (size_t)(q0 + l15) * DHEAD;
        const size_t qrB = kvb + (size_t)(q0 + 16 + l15) * DHEAD;
        qA[0] = *(const bf16x8*)(Qh_g + qrA + quad * 8);
        qA[1] = *(const bf16x8*)(Qh_g + qrA + 32 + quad * 8);
        qB[0] = *(const bf16x8*)(Qh_g + qrB + quad * 8);
        qB[1] = *(const bf16x8*)(Qh_g + qrB + 32 + quad * 8);
    }

    const bool isv = (w >= 2);
    int srow[4], spos[4];
    #pragma unroll
    for (int j = 0; j < 4; ++j) {
        const int c = (w & 1) * 256 + j * 64 + lane;
        srow[j] = c >> 3;
        spos[j] = (c & 7) ^ (srow[j] & 7);
    }

    auto stage = [&](int buf, int kb) {
        short* d = isv ? Vsh[buf] : Ksh[buf];
        const short* src = isv ? (Vth_g + kvb + kb) : (Kh_g + kvb + (size_t)kb * DHEAD);
        #pragma unroll
        for (int j = 0; j < 4; ++j) {
            const short* g = src + (isv ? ((size_t)srow[j] * SEQ + spos[j] * 8)
                                        : ((size_t)srow[j] * DHEAD + spos[j] * 8));
            async_ld16(g, d + ((w & 1) * 256 + j * 64) * 8);
        }
    };

    f32x4 oA[4] = {}, oB[4] = {};
    f32x4 lAv = {}, lBv = {};

    const int kb0 = sk * (SEQ / 2), kb1 = kb0 + SEQ / 2;
    stage(0, kb0);
    int pb = 0;
    for (int kb = kb0; kb < kb1; kb += 64, pb ^= 1) {
        __syncthreads();   // prefetch of buf pb drained; prior reads of pb^1 done
        if (kb + 64 < kb1) stage(pb ^ 1, kb + 64);

        const short* Kb = Ksh[pb];
        const short* Vb = Vsh[pb];

        // ---- S^T = K Q^T for both q-fragments (K frags read once) ----
        #pragma unroll
        for (int mf = 0; mf < 4; ++mf) {
            const int row = mf * 16 + l15;
            const int sw = row & 7;
            bf16x8 kh0 = *(const bf16x8*)(Kb + row * 64 + ((quad ^ sw) * 8));
            bf16x8 kh1 = *(const bf16x8*)(Kb + row * 64 + (((4 + quad) ^ sw) * 8));
            f32x4 cA = {}, cB = {};
            cA = __builtin_amdgcn_mfma_f32_16x16x32_bf16(kh0, qA[0], cA, 0, 0, 0);
            cA = __builtin_amdgcn_mfma_f32_16x16x32_bf16(kh1, qA[1], cA, 0, 0, 0);
            cB = __builtin_amdgcn_mfma_f32_16x16x32_bf16(kh0, qB[0], cB, 0, 0, 0);
            cB = __builtin_amdgcn_mfma_f32_16x16x32_bf16(kh1, qB[1], cB, 0, 0, 0);

            unsigned uA[4], uB[4];
            #pragma unroll
            for (int r = 0; r < 4; ++r) {
                union { float f; unsigned u; } p;
                p.f = __builtin_amdgcn_exp2f(cA[r]);
                uA[r] = p.u;
                p.f = __builtin_amdgcn_exp2f(cB[r]);
                uB[r] = p.u;
            }
            uint2 pkA, pkB;
            pkA.x = __builtin_amdgcn_perm(uA[1], uA[0], 0x07060302u);
            pkA.y = __builtin_amdgcn_perm(uA[3], uA[2], 0x07060302u);
            pkB.x = __builtin_amdgcn_perm(uB[1], uB[0], 0x07060302u);
            pkB.y = __builtin_amdgcn_perm(uB[3], uB[2], 0x07060302u);
            *(uint2*)(&Ph[w][0][l15 * PP + mf * 16 + quad * 4]) = pkA;
            *(uint2*)(&Ph[w][1][l15 * PP + mf * 16 + quad * 4]) = pkB;
        }
        // wave-private LDS: in-order within wave, no barrier needed

        bf16x8 pA0 = *(const bf16x8*)(&Ph[w][0][l15 * PP + quad * 8]);
        bf16x8 pA1 = *(const bf16x8*)(&Ph[w][0][l15 * PP + 32 + quad * 8]);
        bf16x8 pB0 = *(const bf16x8*)(&Ph[w][1][l15 * PP + quad * 8]);
        bf16x8 pB1 = *(const bf16x8*)(&Ph[w][1][l15 * PP + 32 + quad * 8]);

        // ---- l += P * ones (row-aligned with O) ----
        lAv = __builtin_amdgcn_mfma_f32_16x16x32_bf16(pA0, ones, lAv, 0, 0, 0);
        lAv = __builtin_amdgcn_mfma_f32_16x16x32_bf16(pA1, ones, lAv, 0, 0, 0);
        lBv = __builtin_amdgcn_mfma_f32_16x16x32_bf16(pB0, ones, lBv, 0, 0, 0);
        lBv = __builtin_amdgcn_mfma_f32_16x16x32_bf16(pB1, ones, lBv, 0, 0, 0);

        // ---- O += P V for both fragments (V frags read once) ----
        #pragma unroll
        for (int nf = 0; nf < 4; ++nf) {
            const int row = nf * 16 + l15;
            const int sw = row & 7;
            bf16x8 vh0 = *(const bf16x8*)(Vb + row * 64 + ((quad ^ sw) * 8));
            bf16x8 vh1 = *(const bf16x8*)(Vb + row * 64 + (((4 + quad) ^ sw) * 8));
            f32x4 cA = oA[nf], cB = oB[nf];
            cA = __builtin_amdgcn_mfma_f32_16x16x32_bf16(pA0, vh0, cA, 0, 0, 0);
            cA = __builtin_amdgcn_mfma_f32_16x16x32_bf16(pA1, vh1, cA, 0, 0, 0);
            cB = __builtin_amdgcn_mfma_f32_16x16x32_bf16(pB0, vh0, cB, 0, 0, 0);
            cB = __builtin_amdgcn_mfma_f32_16x16x32_bf16(pB1, vh1, cB, 0, 0, 0);
            oA[nf] = cA; oB[nf] = cB;
        }
    }

    // ---- epilogue: write unnormalized partial O (fp32) + partial l ----
    float* op = sk ? op1 : op0;
    float* lg = sk ? l1g : l0g;
    const int b = bh >> 4, hh = bh & 15;
    #pragma unroll
    for (int r = 0; r < 4; ++r) {
        const int qa = q0 + quad * 4 + r;
        if (l15 == 0) {                 // one lane per row writes l
            lg[bh * SEQ + qa] = lAv[r];
            lg[bh * SEQ + qa + 16] = lBv[r];
        }
    }
    #pragma unroll
    for (int nf = 0; nf < 4; ++nf) {
        #pragma unroll
        for (int r = 0; r < 4; ++r) {
            const int qa = q0 + quad * 4 + r;
            const int d = nf * 16 + l15;
            op[(size_t)(b * SEQ + qa) * DMODEL + hh * DHEAD + d] = oA[nf][r];
            op[(size_t)(b * SEQ + qa + 16) * DMODEL + hh * DHEAD + d] = oB[nf][r];
        }
    }
}

// ---------------- combine: aoh = bf16((O0+O1)/(l0+l1)) ----------------
__global__ __launch_bounds__(256) void combine_o(
    const float* __restrict__ op0, const float* __restrict__ op1,
    const float* __restrict__ l0g, const float* __restrict__ l1g,
    short* __restrict__ aoh)
{
    const int i = blockIdx.x * 256 + threadIdx.x;   // 8 elems each; grid 2048
    const size_t e = (size_t)i * 8;
    const int qg = (int)(e >> 10);            // b*S+q
    const int col = (int)(e & 1023);
    const int b = qg >> 11;
    const int q = qg & (SEQ - 1);
    const int bh = b * NHEADS + (col >> 6);
    const float inv = 1.0f / (l0g[bh * SEQ + q] + l1g[bh * SEQ + q]);

    float4 a0 = *(const float4*)(op0 + e);
    float4 a1 = *(const float4*)(op0 + e + 4);
    float4 c0 = *(const float4*)(op1 + e);
    float4 c1 = *(const float4*)(op1 + e + 4);
    bf16x8 H;
    H[0] = f2bf((a0.x + c0.x) * inv);
    H[1] = f2bf((a0.y + c0.y) * inv);
    H[2] = f2bf((a0.z + c0.z) * inv);
    H[3] = f2bf((a0.w + c0.w) * inv);
    H[4] = f2bf((a1.x + c1.x) * inv);
    H[5] = f2bf((a1.y + c1.y) * inv);
    H[6] = f2bf((a1.z + c1.z) * inv);
    H[7] = f2bf((a1.w + c1.w) * inv);
    *((bf16x8*)aoh + i) = H;
}

// ---------------- launch ----------------
extern "C" void kernel_launch(void* const* d_in, const int* in_sizes, int n_in,
                              void* d_out, int out_size, void* d_ws, size_t ws_size,
                              hipStream_t stream) {
    const float* x  = (const float*)d_in[0];
    // d_in[1] = pH : softmax shift-invariant, ignored
    const float* Wq = (const float*)d_in[2];
    const float* bq = (const float*)d_in[3];
    const float* Wk = (const float*)d_in[4];
    const float* bk = (const float*)d_in[5];
    const float* Wv = (const float*)d_in[6];
    const float* bv = (const float*)d_in[7];
    const float* Wo = (const float*)d_in[8];
    const float* bo = (const float*)d_in[9];
    float* out = (float*)d_out;

    char* ws = (char*)d_ws;
    const size_t MB = 1024 * 1024;
    short* qh  = (short*)(ws + 0 * MB);      // 8 MB
    short* kh  = (short*)(ws + 16 * MB);     // 8 MB
    short* vth = (short*)(ws + 32 * MB);     // 8 MB
    short* aoh = (short*)(ws + 48 * MB);     // 8 MB
    float* op0 = (float*)(ws + 56 * MB);     // 16 MB (overlays free xhi after QKV)
    short* xhi = (short*)(ws + 64 * MB);     // 8 MB (dead after QKV GEMM)
    float* op1 = (float*)(ws + 72 * MB);     // 16 MB (overlays free wqkv after QKV)
    short* wqkv_hi = (short*)(ws + 80 * MB); // 6 MB (dead after QKV GEMM)
    float* l0g = (float*)(ws + 88 * MB);     // 256 KB
    float* l1g = (float*)(ws + 89 * MB);     // 256 KB
    short* wto_hi  = (short*)(ws + 92 * MB); // 2 MB

    dim3 blk(256);

    hipLaunchKernelGGL(prep, dim3(2048 + 1024), blk, 0, stream,
                       x, xhi, Wq, Wk, Wv, Wo, wqkv_hi, wto_hi);

    const float qscale = 0.125f * 1.44269504088896f;   // fold 1/sqrt(dh)*log2(e)
    hipLaunchKernelGGL(mfma_gemm, dim3(3072 / 128, MROWS / 128), blk, 0, stream,
                       xhi, wqkv_hi, bq, bk, bv,
                       qh, kh, vth, (float*)nullptr, 0, qscale);

    hipLaunchKernelGGL(attn_mfma, dim3(BATCH * NHEADS * (SEQ / 128) * 2), blk, 0, stream,
                       qh, kh, vth, op0, op1, l0g, l1g);

    hipLaunchKernelGGL(combine_o, dim3(MROWS * DMODEL / 8 / 256), blk, 0, stream,
                       op0, op1, l0g, l1g, aoh);

    hipLaunchKernelGGL(mfma_gemm, dim3(1024 / 128, MROWS / 128), blk, 0, stream,
                       aoh, wto_hi, bo, bo, bo,
                       (short*)nullptr, (short*)nullptr, (short*)nullptr,
                       out, 1, 1.0f);
}

// Round 12
// 205.926 us; speedup vs baseline: 1.0390x; 1.0390x over previous
//
#include <hip/hip_runtime.h>
#include <hip/hip_bf16.h>
#include <math.h>

// Problem constants
#define BATCH 2
#define SEQ   2048
#define DMODEL 1024
#define NHEADS 16
#define DHEAD 64
#define MROWS (BATCH*SEQ)   // 4096

typedef __attribute__((ext_vector_type(8))) short bf16x8;
typedef __attribute__((ext_vector_type(4))) short bf16x4;
typedef __attribute__((ext_vector_type(4))) float f32x4;

__device__ __forceinline__ short f2bf(float f) {   // RNE float->bf16
    union { float f; unsigned u; } c; c.f = f;
    unsigned r = (c.u + 0x7fffu + ((c.u >> 16) & 1u)) >> 16;
    return (short)r;
}
__device__ __forceinline__ float bf2f(short h) {
    union { unsigned u; float f; } c; c.u = ((unsigned)(unsigned short)h) << 16;
    return c.f;
}

__device__ __forceinline__ void async_ld16(const void* g, void* l) {
    __builtin_amdgcn_global_load_lds(
        (const __attribute__((address_space(1))) unsigned*)g,
        (__attribute__((address_space(3))) unsigned*)l, 16, 0, 0);
}

// ---------------- fused prep: convert x -> bf16 AND transpose 4 weights ----------------
__global__ __launch_bounds__(256) void prep(
    const float* __restrict__ x, short* __restrict__ xhi,
    const float* __restrict__ W0, const float* __restrict__ W1,
    const float* __restrict__ W2, const float* __restrict__ W3,
    short* __restrict__ oqkv, short* __restrict__ oo)
{
    __shared__ float T[64][65];
    const int tid = threadIdx.x;
    if (blockIdx.x < 2048) {
        const int i = blockIdx.x * 256 + tid;
        const float4* p = (const float4*)x + (size_t)i * 2;
        float4 a = p[0], b = p[1];
        float v[8] = {a.x, a.y, a.z, a.w, b.x, b.y, b.z, b.w};
        bf16x8 H;
        #pragma unroll
        for (int j = 0; j < 8; ++j) H[j] = f2bf(v[j]);
        *((bf16x8*)xhi + i) = H;
        return;
    }
    const int bi = blockIdx.x - 2048;
    const int z = bi >> 8;
    const int t = bi & 255;
    const float* W = (z == 0) ? W0 : (z == 1) ? W1 : (z == 2) ? W2 : W3;
    short* out = (z < 3) ? (oqkv + (size_t)z * 1024 * 1024) : oo;
    const int n0 = (t & 15) * 64, k0 = (t >> 4) * 64;
    #pragma unroll
    for (int i = 0; i < 16; ++i) {
        const int idx = tid + i * 256;
        const int r = idx >> 6, c = idx & 63;
        T[r][c] = W[(size_t)(k0 + r) * DMODEL + n0 + c];
    }
    __syncthreads();
    #pragma unroll
    for (int i = 0; i < 4; ++i) {
        const int idx = tid + i * 256;
        const int r = idx >> 4, g = idx & 15;
        bf16x4 H;
        #pragma unroll
        for (int j = 0; j < 4; ++j)
            H[j] = f2bf(T[g * 4 + j][r]);
        *(bf16x4*)(out + (size_t)(n0 + r) * DMODEL + k0 + g * 4) = H;
    }
}

// ---------------- MFMA GEMM: C = A[M,K] * Bt[N,K]^T, 1-term bf16 ----------------
#define GBK 64

__global__ __launch_bounds__(256) void mfma_gemm(
    const short* __restrict__ Ahi, const short* __restrict__ Bthi,
    const float* __restrict__ b0, const float* __restrict__ b1, const float* __restrict__ b2,
    short* __restrict__ oqh, short* __restrict__ okh, short* __restrict__ ovh,
    float* __restrict__ outf, int mode, float qscale)
{
    __shared__ short Ah[128 * GBK], Bh[128 * GBK];   // 16 KB each

    const int tid  = threadIdx.x;
    const int lane = tid & 63;
    const int w    = tid >> 6;
    const int quad = lane >> 4;
    const int l15  = lane & 15;
    const int wr   = w >> 1, wc = w & 1;
    const int m0   = blockIdx.y * 128;
    const int n0   = blockIdx.x * 128;
    const int K    = DMODEL;

    f32x4 acc[4][4] = {};

    int srow[4], spos[4];
    #pragma unroll
    for (int j = 0; j < 4; ++j) {
        const int c = w * 256 + j * 64 + lane;
        srow[j] = c >> 3;
        spos[j] = (c & 7) ^ (srow[j] & 7);
    }

    for (int k0 = 0; k0 < K; k0 += GBK) {
        __syncthreads();
        #pragma unroll
        for (int j = 0; j < 4; ++j) {
            const int cB = (w * 256 + j * 64) * 8;
            async_ld16(Ahi + (size_t)(m0 + srow[j]) * K + k0 + spos[j] * 8, Ah + cB);
            async_ld16(Bthi + (size_t)(n0 + srow[j]) * K + k0 + spos[j] * 8, Bh + cB);
        }
        __syncthreads();

        #pragma unroll
        for (int s = 0; s < 2; ++s) {
            bf16x8 afh[4], bfh[4];
            #pragma unroll
            for (int mi = 0; mi < 4; ++mi) {
                const int row = wr * 64 + mi * 16 + l15;
                const int pos = (s * 4 + quad) ^ (row & 7);
                afh[mi] = *(const bf16x8*)(Ah + row * GBK + pos * 8);
            }
            #pragma unroll
            for (int ni = 0; ni < 4; ++ni) {
                const int row = wc * 64 + ni * 16 + l15;
                const int pos = (s * 4 + quad) ^ (row & 7);
                bfh[ni] = *(const bf16x8*)(Bh + row * GBK + pos * 8);
            }
            #pragma unroll
            for (int mi = 0; mi < 4; ++mi)
                #pragma unroll
                for (int ni = 0; ni < 4; ++ni)
                    acc[mi][ni] = __builtin_amdgcn_mfma_f32_16x16x32_bf16(
                        afh[mi], bfh[ni], acc[mi][ni], 0, 0, 0);
        }
    }

    const int nbase = n0 + wc * 64;
    if (mode == 1) {
        #pragma unroll
        for (int mi = 0; mi < 4; ++mi)
            #pragma unroll
            for (int ni = 0; ni < 4; ++ni)
                #pragma unroll
                for (int r = 0; r < 4; ++r) {
                    const int m = m0 + wr * 64 + mi * 16 + quad * 4 + r;
                    const int nn = nbase + ni * 16 + l15;
                    outf[(size_t)m * DMODEL + nn] = acc[mi][ni][r] + b0[nn];
                }
    } else {
        __syncthreads();   // all waves done reading Ah/Bh; reuse as scratch
        short* scr = (w < 2) ? (Ah + w * 4096) : (Bh + (w - 2) * 4096);  // 8 KB/wave
        const int which = nbase >> 10;
        const int hh = (nbase & 1023) >> 6;
        const int mb = m0 + wr * 64;
        const int b = mb >> 11, sbase = mb & (SEQ - 1);

        if (which < 2) {
            const float* bias = which ? b1 : b0;
            short* dstp = which ? okh : oqh;
            const float scl = which ? 1.0f : qscale;
            #pragma unroll
            for (int mi = 0; mi < 4; ++mi)
                #pragma unroll
                for (int ni = 0; ni < 4; ++ni)
                    #pragma unroll
                    for (int r = 0; r < 4; ++r) {
                        const int sloc = mi * 16 + quad * 4 + r;
                        const int dloc = ni * 16 + l15;
                        const int nn = (nbase + ni * 16 + l15) & 1023;
                        scr[sloc * 64 + (((dloc >> 3) ^ (sloc & 7)) * 8) + (dloc & 7)] =
                            f2bf((acc[mi][ni][r] + bias[nn]) * scl);
                    }
            #pragma unroll
            for (int i = 0; i < 8; ++i) {
                const int sloc = i * 8 + (lane >> 3);
                const int cph = (lane & 7) ^ (sloc & 7);
                bf16x8 row = *(const bf16x8*)(scr + sloc * 64 + cph * 8);
                const int dloc = (lane & 7) * 8;
                *(bf16x8*)(dstp + ((size_t)(b * NHEADS + hh) * SEQ + sbase + sloc) * DHEAD + dloc) = row;
            }
        } else {
            #pragma unroll
            for (int mi = 0; mi < 4; ++mi)
                #pragma unroll
                for (int ni = 0; ni < 4; ++ni)
                    #pragma unroll
                    for (int r = 0; r < 4; ++r) {
                        const int sloc = mi * 16 + quad * 4 + r;
                        const int dloc = ni * 16 + l15;
                        const int nn = (nbase + ni * 16 + l15) & 1023;
                        scr[dloc * 64 + (((sloc >> 3) ^ (dloc & 7)) * 8) + (sloc & 7)] =
                            f2bf(acc[mi][ni][r] + b2[nn]);
                    }
            #pragma unroll
            for (int i = 0; i < 8; ++i) {
                const int dloc = i * 8 + (lane >> 3);
                const int cph = (lane & 7) ^ (dloc & 7);
                bf16x8 row = *(const bf16x8*)(scr + dloc * 64 + cph * 8);
                const int sg = sbase + (lane & 7) * 8;
                *(bf16x8*)(ovh + ((size_t)(b * NHEADS + hh) * DHEAD + dloc) * SEQ + sg) = row;
            }
        }
    }
}

// ---------------- MFMA flash attention v10: split-K x2, 32 KB LDS ----------------
// Single-buffered K/V (inter-block overlap replaces dbuf at 4 blocks/CU),
// compact XOR-swizzled P tiles (no padding), bf16 unnormalized partials.
__global__ __launch_bounds__(256) void attn_mfma(
    const short* __restrict__ Qh_g, const short* __restrict__ Kh_g,
    const short* __restrict__ Vth_g,
    short* __restrict__ op0, short* __restrict__ op1,
    float* __restrict__ l0g, float* __restrict__ l1g)
{
    __shared__ short Ksh[4096];          // [key][d] swizzled, 8 KB
    __shared__ short Vsh[4096];          // [d][s] swizzled, 8 KB
    __shared__ short Ph[4][2][1024];     // [wave][qfrag][16x64 swizzled], 16 KB

    const int tid  = threadIdx.x;
    const int lane = tid & 63;
    const int w    = tid >> 6;
    const int quad = lane >> 4;
    const int l15  = lane & 15;

    const int bh    = blockIdx.x & 31;        // XCD-local head
    const int sk    = (blockIdx.x >> 5) & 1;  // K-split half
    const int qtile = blockIdx.x >> 6;        // 0..15
    const int q0    = qtile * 128 + w * 32;
    const size_t kvb = (size_t)bh * SEQ * DHEAD;

    bf16x8 ones;
    #pragma unroll
    for (int j = 0; j < 8; ++j) ones[j] = (short)0x3f80;   // bf16 1.0

    bf16x8 qA[2], qB[2];
    {
        const size_t qrA = kvb + (size_t)(q0 + l15) * DHEAD;
        const size_t qrB = kvb + (size_t)(q0 + 16 + l15) * DHEAD;
        qA[0] = *(const bf16x8*)(Qh_g + qrA + quad * 8);
        qA[1] = *(const bf16x8*)(Qh_g + qrA + 32 + quad * 8);
        qB[0] = *(const bf16x8*)(Qh_g + qrB + quad * 8);
        qB[1] = *(const bf16x8*)(Qh_g + qrB + 32 + quad * 8);
    }

    const bool isv = (w >= 2);
    short* dst = isv ? Vsh : Ksh;
    int srow[4], spos[4];
    #pragma unroll
    for (int j = 0; j < 4; ++j) {
        const int c = (w & 1) * 256 + j * 64 + lane;
        srow[j] = c >> 3;
        spos[j] = (c & 7) ^ (srow[j] & 7);
    }

    f32x4 oA[4] = {}, oB[4] = {};
    f32x4 lAv = {}, lBv = {};

    const int kb0 = sk * (SEQ / 2), kb1 = kb0 + SEQ / 2;
    for (int kb = kb0; kb < kb1; kb += 64) {
        __syncthreads();   // prior iteration's LDS reads complete
        {
            const short* src = isv ? (Vth_g + kvb + kb) : (Kh_g + kvb + (size_t)kb * DHEAD);
            #pragma unroll
            for (int j = 0; j < 4; ++j) {
                const short* g = src + (isv ? ((size_t)srow[j] * SEQ + spos[j] * 8)
                                            : ((size_t)srow[j] * DHEAD + spos[j] * 8));
                async_ld16(g, dst + ((w & 1) * 256 + j * 64) * 8);
            }
        }
        __syncthreads();   // staged data visible

        // ---- S^T = K Q^T for both q-fragments (K frags read once) ----
        #pragma unroll
        for (int mf = 0; mf < 4; ++mf) {
            const int row = mf * 16 + l15;
            const int sw = row & 7;
            bf16x8 kh0 = *(const bf16x8*)(Ksh + row * 64 + ((quad ^ sw) * 8));
            bf16x8 kh1 = *(const bf16x8*)(Ksh + row * 64 + (((4 + quad) ^ sw) * 8));
            f32x4 cA = {}, cB = {};
            cA = __builtin_amdgcn_mfma_f32_16x16x32_bf16(kh0, qA[0], cA, 0, 0, 0);
            cA = __builtin_amdgcn_mfma_f32_16x16x32_bf16(kh1, qA[1], cA, 0, 0, 0);
            cB = __builtin_amdgcn_mfma_f32_16x16x32_bf16(kh0, qB[0], cB, 0, 0, 0);
            cB = __builtin_amdgcn_mfma_f32_16x16x32_bf16(kh1, qB[1], cB, 0, 0, 0);

            unsigned uA[4], uB[4];
            #pragma unroll
            for (int r = 0; r < 4; ++r) {
                union { float f; unsigned u; } p;
                p.f = __builtin_amdgcn_exp2f(cA[r]);
                uA[r] = p.u;
                p.f = __builtin_amdgcn_exp2f(cB[r]);
                uB[r] = p.u;
            }
            uint2 pkA, pkB;
            pkA.x = __builtin_amdgcn_perm(uA[1], uA[0], 0x07060302u);
            pkA.y = __builtin_amdgcn_perm(uA[3], uA[2], 0x07060302u);
            pkB.x = __builtin_amdgcn_perm(uB[1], uB[0], 0x07060302u);
            pkB.y = __builtin_amdgcn_perm(uB[3], uB[2], 0x07060302u);
            // compact P: row=l15 (q), cols mf*16+quad*4..+4; 16B-chunk XOR-8 swizzle
            const int pc = (mf * 2 + (quad >> 1)) ^ (l15 & 7);
            const int paddr = l15 * 64 + pc * 8 + (quad & 1) * 4;
            *(uint2*)(&Ph[w][0][paddr]) = pkA;
            *(uint2*)(&Ph[w][1][paddr]) = pkB;
        }
        // wave-private LDS: in-order within wave, no barrier needed

        const int psw = l15 & 7;
        bf16x8 pA0 = *(const bf16x8*)(&Ph[w][0][l15 * 64 + ((quad ^ psw) * 8)]);
        bf16x8 pA1 = *(const bf16x8*)(&Ph[w][0][l15 * 64 + (((4 + quad) ^ psw) * 8)]);
        bf16x8 pB0 = *(const bf16x8*)(&Ph[w][1][l15 * 64 + ((quad ^ psw) * 8)]);
        bf16x8 pB1 = *(const bf16x8*)(&Ph[w][1][l15 * 64 + (((4 + quad) ^ psw) * 8)]);

        // ---- l += P * ones (row-aligned with O) ----
        lAv = __builtin_amdgcn_mfma_f32_16x16x32_bf16(pA0, ones, lAv, 0, 0, 0);
        lAv = __builtin_amdgcn_mfma_f32_16x16x32_bf16(pA1, ones, lAv, 0, 0, 0);
        lBv = __builtin_amdgcn_mfma_f32_16x16x32_bf16(pB0, ones, lBv, 0, 0, 0);
        lBv = __builtin_amdgcn_mfma_f32_16x16x32_bf16(pB1, ones, lBv, 0, 0, 0);

        // ---- O += P V for both fragments (V frags read once) ----
        #pragma unroll
        for (int nf = 0; nf < 4; ++nf) {
            const int row = nf * 16 + l15;
            const int sw = row & 7;
            bf16x8 vh0 = *(const bf16x8*)(Vsh + row * 64 + ((quad ^ sw) * 8));
            bf16x8 vh1 = *(const bf16x8*)(Vsh + row * 64 + (((4 + quad) ^ sw) * 8));
            f32x4 cA = oA[nf], cB = oB[nf];
            cA = __builtin_amdgcn_mfma_f32_16x16x32_bf16(pA0, vh0, cA, 0, 0, 0);
            cA = __builtin_amdgcn_mfma_f32_16x16x32_bf16(pA1, vh1, cA, 0, 0, 0);
            cB = __builtin_amdgcn_mfma_f32_16x16x32_bf16(pB0, vh0, cB, 0, 0, 0);
            cB = __builtin_amdgcn_mfma_f32_16x16x32_bf16(pB1, vh1, cB, 0, 0, 0);
            oA[nf] = cA; oB[nf] = cB;
        }
    }

    // ---- epilogue: bf16 unnormalized partial O + fp32 partial l ----
    short* op = sk ? op1 : op0;
    float* lg = sk ? l1g : l0g;
    const int b = bh >> 4, hh = bh & 15;
    #pragma unroll
    for (int r = 0; r < 4; ++r) {
        const int qa = q0 + quad * 4 + r;
        if (l15 == 0) {
            lg[bh * SEQ + qa] = lAv[r];
            lg[bh * SEQ + qa + 16] = lBv[r];
        }
    }
    #pragma unroll
    for (int nf = 0; nf < 4; ++nf) {
        #pragma unroll
        for (int r = 0; r < 4; ++r) {
            const int qa = q0 + quad * 4 + r;
            const int d = nf * 16 + l15;
            op[(size_t)(b * SEQ + qa) * DMODEL + hh * DHEAD + d] = f2bf(oA[nf][r]);
            op[(size_t)(b * SEQ + qa + 16) * DMODEL + hh * DHEAD + d] = f2bf(oB[nf][r]);
        }
    }
}

// ---------------- combine: aoh = bf16((O0+O1)/(l0+l1)), bf16 inputs ----------------
__global__ __launch_bounds__(256) void combine_o(
    const short* __restrict__ op0, const short* __restrict__ op1,
    const float* __restrict__ l0g, const float* __restrict__ l1g,
    short* __restrict__ aoh)
{
    const int i = blockIdx.x * 256 + threadIdx.x;   // 8 elems each; grid 2048
    const size_t e = (size_t)i * 8;
    const int qg = (int)(e >> 10);
    const int col = (int)(e & 1023);
    const int b = qg >> 11;
    const int q = qg & (SEQ - 1);
    const int bh = b * NHEADS + (col >> 6);
    const float inv = 1.0f / (l0g[bh * SEQ + q] + l1g[bh * SEQ + q]);

    bf16x8 a = *((const bf16x8*)op0 + i);
    bf16x8 c = *((const bf16x8*)op1 + i);
    bf16x8 H;
    #pragma unroll
    for (int j = 0; j < 8; ++j)
        H[j] = f2bf((bf2f(a[j]) + bf2f(c[j])) * inv);
    *((bf16x8*)aoh + i) = H;
}

// ---------------- launch ----------------
extern "C" void kernel_launch(void* const* d_in, const int* in_sizes, int n_in,
                              void* d_out, int out_size, void* d_ws, size_t ws_size,
                              hipStream_t stream) {
    const float* x  = (const float*)d_in[0];
    // d_in[1] = pH : softmax shift-invariant, ignored
    const float* Wq = (const float*)d_in[2];
    const float* bq = (const float*)d_in[3];
    const float* Wk = (const float*)d_in[4];
    const float* bk = (const float*)d_in[5];
    const float* Wv = (const float*)d_in[6];
    const float* bv = (const float*)d_in[7];
    const float* Wo = (const float*)d_in[8];
    const float* bo = (const float*)d_in[9];
    float* out = (float*)d_out;

    char* ws = (char*)d_ws;
    const size_t MB = 1024 * 1024;
    short* qh  = (short*)(ws + 0 * MB);      // 8 MB
    short* kh  = (short*)(ws + 16 * MB);     // 8 MB
    short* vth = (short*)(ws + 32 * MB);     // 8 MB
    short* aoh = (short*)(ws + 48 * MB);     // 8 MB
    short* op0 = (short*)(ws + 56 * MB);     // 8 MB bf16 partial
    short* xhi = (short*)(ws + 64 * MB);     // 8 MB (dead after QKV GEMM)
    short* op1 = (short*)(ws + 72 * MB);     // 8 MB bf16 partial
    short* wqkv_hi = (short*)(ws + 80 * MB); // 6 MB [3072][1024]
    float* l0g = (float*)(ws + 88 * MB);     // 256 KB
    float* l1g = (float*)(ws + 89 * MB);     // 256 KB
    short* wto_hi  = (short*)(ws + 92 * MB); // 2 MB

    dim3 blk(256);

    hipLaunchKernelGGL(prep, dim3(2048 + 1024), blk, 0, stream,
                       x, xhi, Wq, Wk, Wv, Wo, wqkv_hi, wto_hi);

    const float qscale = 0.125f * 1.44269504088896f;   // fold 1/sqrt(dh)*log2(e)
    hipLaunchKernelGGL(mfma_gemm, dim3(3072 / 128, MROWS / 128), blk, 0, stream,
                       xhi, wqkv_hi, bq, bk, bv,
                       qh, kh, vth, (float*)nullptr, 0, qscale);

    hipLaunchKernelGGL(attn_mfma, dim3(BATCH * NHEADS * (SEQ / 128) * 2), blk, 0, stream,
                       qh, kh, vth, op0, op1, l0g, l1g);

    hipLaunchKernelGGL(combine_o, dim3(MROWS * DMODEL / 8 / 256), blk, 0, stream,
                       op0, op1, l0g, l1g, aoh);

    hipLaunchKernelGGL(mfma_gemm, dim3(1024 / 128, MROWS / 128), blk, 0, stream,
                       aoh, wto_hi, bo, bo, bo,
                       (short*)nullptr, (short*)nullptr, (short*)nullptr,
                       out, 1, 1.0f);
}

// Round 13
// 205.447 us; speedup vs baseline: 1.0414x; 1.0023x over previous
//
#include <hip/hip_runtime.h>
#include <hip/hip_bf16.h>
#include <math.h>

// Problem constants
#define BATCH 2
#define SEQ   2048
#define DMODEL 1024
#define NHEADS 16
#define DHEAD 64
#define MROWS (BATCH*SEQ)   // 4096

typedef __attribute__((ext_vector_type(8))) short bf16x8;
typedef __attribute__((ext_vector_type(4))) short bf16x4;
typedef __attribute__((ext_vector_type(4))) float f32x4;

__device__ __forceinline__ short f2bf(float f) {   // RNE float->bf16
    union { float f; unsigned u; } c; c.f = f;
    unsigned r = (c.u + 0x7fffu + ((c.u >> 16) & 1u)) >> 16;
    return (short)r;
}
__device__ __forceinline__ float bf2f(short h) {
    union { unsigned u; float f; } c; c.u = ((unsigned)(unsigned short)h) << 16;
    return c.f;
}

__device__ __forceinline__ void async_ld16(const void* g, void* l) {
    __builtin_amdgcn_global_load_lds(
        (const __attribute__((address_space(1))) unsigned*)g,
        (__attribute__((address_space(3))) unsigned*)l, 16, 0, 0);
}

// ---------------- fused prep: convert x -> bf16 AND transpose 4 weights ----------------
__global__ __launch_bounds__(256) void prep(
    const float* __restrict__ x, short* __restrict__ xhi,
    const float* __restrict__ W0, const float* __restrict__ W1,
    const float* __restrict__ W2, const float* __restrict__ W3,
    short* __restrict__ oqkv, short* __restrict__ oo)
{
    __shared__ float T[64][65];
    const int tid = threadIdx.x;
    if (blockIdx.x < 2048) {
        const int i = blockIdx.x * 256 + tid;
        const float4* p = (const float4*)x + (size_t)i * 2;
        float4 a = p[0], b = p[1];
        float v[8] = {a.x, a.y, a.z, a.w, b.x, b.y, b.z, b.w};
        bf16x8 H;
        #pragma unroll
        for (int j = 0; j < 8; ++j) H[j] = f2bf(v[j]);
        *((bf16x8*)xhi + i) = H;
        return;
    }
    const int bi = blockIdx.x - 2048;
    const int z = bi >> 8;
    const int t = bi & 255;
    const float* W = (z == 0) ? W0 : (z == 1) ? W1 : (z == 2) ? W2 : W3;
    short* out = (z < 3) ? (oqkv + (size_t)z * 1024 * 1024) : oo;
    const int n0 = (t & 15) * 64, k0 = (t >> 4) * 64;
    #pragma unroll
    for (int i = 0; i < 16; ++i) {
        const int idx = tid + i * 256;
        const int r = idx >> 6, c = idx & 63;
        T[r][c] = W[(size_t)(k0 + r) * DMODEL + n0 + c];
    }
    __syncthreads();
    #pragma unroll
    for (int i = 0; i < 4; ++i) {
        const int idx = tid + i * 256;
        const int r = idx >> 4, g = idx & 15;
        bf16x4 H;
        #pragma unroll
        for (int j = 0; j < 4; ++j)
            H[j] = f2bf(T[g * 4 + j][r]);
        *(bf16x4*)(out + (size_t)(n0 + r) * DMODEL + k0 + g * 4) = H;
    }
}

// ---------------- MFMA GEMM (QKV): C = A[M,K] * Bt[N,K]^T, 1-term bf16 ----------------
// 128x128 tile; emits q/k bf16 [B,H,S,64], v bf16 transposed [B,H,64,S] via
// LDS-scratch coalesced epilogue.
#define GBK 64

__global__ __launch_bounds__(256) void mfma_gemm(
    const short* __restrict__ Ahi, const short* __restrict__ Bthi,
    const float* __restrict__ b0, const float* __restrict__ b1, const float* __restrict__ b2,
    short* __restrict__ oqh, short* __restrict__ okh, short* __restrict__ ovh,
    float qscale)
{
    __shared__ short Ah[128 * GBK], Bh[128 * GBK];   // 16 KB each

    const int tid  = threadIdx.x;
    const int lane = tid & 63;
    const int w    = tid >> 6;
    const int quad = lane >> 4;
    const int l15  = lane & 15;
    const int wr   = w >> 1, wc = w & 1;
    const int m0   = blockIdx.y * 128;
    const int n0   = blockIdx.x * 128;
    const int K    = DMODEL;

    f32x4 acc[4][4] = {};

    int srow[4], spos[4];
    #pragma unroll
    for (int j = 0; j < 4; ++j) {
        const int c = w * 256 + j * 64 + lane;
        srow[j] = c >> 3;
        spos[j] = (c & 7) ^ (srow[j] & 7);
    }

    for (int k0 = 0; k0 < K; k0 += GBK) {
        __syncthreads();
        #pragma unroll
        for (int j = 0; j < 4; ++j) {
            const int cB = (w * 256 + j * 64) * 8;
            async_ld16(Ahi + (size_t)(m0 + srow[j]) * K + k0 + spos[j] * 8, Ah + cB);
            async_ld16(Bthi + (size_t)(n0 + srow[j]) * K + k0 + spos[j] * 8, Bh + cB);
        }
        __syncthreads();

        #pragma unroll
        for (int s = 0; s < 2; ++s) {
            bf16x8 afh[4], bfh[4];
            #pragma unroll
            for (int mi = 0; mi < 4; ++mi) {
                const int row = wr * 64 + mi * 16 + l15;
                const int pos = (s * 4 + quad) ^ (row & 7);
                afh[mi] = *(const bf16x8*)(Ah + row * GBK + pos * 8);
            }
            #pragma unroll
            for (int ni = 0; ni < 4; ++ni) {
                const int row = wc * 64 + ni * 16 + l15;
                const int pos = (s * 4 + quad) ^ (row & 7);
                bfh[ni] = *(const bf16x8*)(Bh + row * GBK + pos * 8);
            }
            #pragma unroll
            for (int mi = 0; mi < 4; ++mi)
                #pragma unroll
                for (int ni = 0; ni < 4; ++ni)
                    acc[mi][ni] = __builtin_amdgcn_mfma_f32_16x16x32_bf16(
                        afh[mi], bfh[ni], acc[mi][ni], 0, 0, 0);
        }
    }

    const int nbase = n0 + wc * 64;
    __syncthreads();   // all waves done reading Ah/Bh; reuse as scratch
    short* scr = (w < 2) ? (Ah + w * 4096) : (Bh + (w - 2) * 4096);  // 8 KB/wave
    const int which = nbase >> 10;               // 0=q, 1=k, 2=v (wave-uniform)
    const int hh = (nbase & 1023) >> 6;          // head
    const int mb = m0 + wr * 64;
    const int b = mb >> 11, sbase = mb & (SEQ - 1);

    if (which < 2) {
        const float* bias = which ? b1 : b0;
        short* dstp = which ? okh : oqh;
        const float scl = which ? 1.0f : qscale;
        #pragma unroll
        for (int mi = 0; mi < 4; ++mi)
            #pragma unroll
            for (int ni = 0; ni < 4; ++ni)
                #pragma unroll
                for (int r = 0; r < 4; ++r) {
                    const int sloc = mi * 16 + quad * 4 + r;
                    const int dloc = ni * 16 + l15;
                    const int nn = (nbase + ni * 16 + l15) & 1023;
                    scr[sloc * 64 + (((dloc >> 3) ^ (sloc & 7)) * 8) + (dloc & 7)] =
                        f2bf((acc[mi][ni][r] + bias[nn]) * scl);
                }
        #pragma unroll
        for (int i = 0; i < 8; ++i) {
            const int sloc = i * 8 + (lane >> 3);
            const int cph = (lane & 7) ^ (sloc & 7);
            bf16x8 row = *(const bf16x8*)(scr + sloc * 64 + cph * 8);
            const int dloc = (lane & 7) * 8;
            *(bf16x8*)(dstp + ((size_t)(b * NHEADS + hh) * SEQ + sbase + sloc) * DHEAD + dloc) = row;
        }
    } else {
        #pragma unroll
        for (int mi = 0; mi < 4; ++mi)
            #pragma unroll
            for (int ni = 0; ni < 4; ++ni)
                #pragma unroll
                for (int r = 0; r < 4; ++r) {
                    const int sloc = mi * 16 + quad * 4 + r;
                    const int dloc = ni * 16 + l15;
                    const int nn = (nbase + ni * 16 + l15) & 1023;
                    scr[dloc * 64 + (((sloc >> 3) ^ (dloc & 7)) * 8) + (sloc & 7)] =
                        f2bf(acc[mi][ni][r] + b2[nn]);
                }
        #pragma unroll
        for (int i = 0; i < 8; ++i) {
            const int dloc = i * 8 + (lane >> 3);
            const int cph = (lane & 7) ^ (dloc & 7);
            bf16x8 row = *(const bf16x8*)(scr + dloc * 64 + cph * 8);
            const int sg = sbase + (lane & 7) * 8;
            *(bf16x8*)(ovh + ((size_t)(b * NHEADS + hh) * DHEAD + dloc) * SEQ + sg) = row;
        }
    }
}

// ---------------- O-proj GEMM: 64x128 tile, grid 512 (2 blocks/CU) ----------------
// out[M,1024] fp32 = aoh[M,1024]bf16 * wto[1024,1024]^T + bo
__global__ __launch_bounds__(256) void ogemm(
    const short* __restrict__ Ahi, const short* __restrict__ Bthi,
    const float* __restrict__ b0, float* __restrict__ outf)
{
    __shared__ short Ah[64 * 64], Bh[128 * 64];   // 8 KB + 16 KB

    const int tid  = threadIdx.x;
    const int lane = tid & 63;
    const int w    = tid >> 6;
    const int quad = lane >> 4;
    const int l15  = lane & 15;
    const int wr   = w >> 1, wc = w & 1;
    const int m0   = blockIdx.y * 64;
    const int n0   = blockIdx.x * 128;
    const int K    = DMODEL;

    f32x4 acc[2][4] = {};

    for (int k0 = 0; k0 < K; k0 += 64) {
        __syncthreads();
        // unified staging: 1536 chunks (A:512, B:1024); 6 wave-uniform calls/wave
        #pragma unroll
        for (int j = 0; j < 6; ++j) {
            const int base = w * 384 + j * 64;   // multiple of 64; A/B split at 512
            const int c = base + lane;
            if (base < 512) {
                const int row = c >> 3, pos = (c & 7) ^ (row & 7);
                async_ld16(Ahi + (size_t)(m0 + row) * K + k0 + pos * 8, Ah + base * 8);
            } else {
                const int cb = c - 512;
                const int row = cb >> 3, pos = (cb & 7) ^ (row & 7);
                async_ld16(Bthi + (size_t)(n0 + row) * K + k0 + pos * 8, Bh + (base - 512) * 8);
            }
        }
        __syncthreads();

        #pragma unroll
        for (int s = 0; s < 2; ++s) {
            bf16x8 afh[2], bfh[4];
            #pragma unroll
            for (int mi = 0; mi < 2; ++mi) {
                const int row = wr * 32 + mi * 16 + l15;
                const int pos = (s * 4 + quad) ^ (row & 7);
                afh[mi] = *(const bf16x8*)(Ah + row * 64 + pos * 8);
            }
            #pragma unroll
            for (int ni = 0; ni < 4; ++ni) {
                const int row = wc * 64 + ni * 16 + l15;
                const int pos = (s * 4 + quad) ^ (row & 7);
                bfh[ni] = *(const bf16x8*)(Bh + row * 64 + pos * 8);
            }
            #pragma unroll
            for (int mi = 0; mi < 2; ++mi)
                #pragma unroll
                for (int ni = 0; ni < 4; ++ni)
                    acc[mi][ni] = __builtin_amdgcn_mfma_f32_16x16x32_bf16(
                        afh[mi], bfh[ni], acc[mi][ni], 0, 0, 0);
        }
    }

    #pragma unroll
    for (int mi = 0; mi < 2; ++mi)
        #pragma unroll
        for (int ni = 0; ni < 4; ++ni)
            #pragma unroll
            for (int r = 0; r < 4; ++r) {
                const int m = m0 + wr * 32 + mi * 16 + quad * 4 + r;
                const int nn = n0 + wc * 64 + ni * 16 + l15;
                outf[(size_t)m * DMODEL + nn] = acc[mi][ni][r] + b0[nn];
            }
}

// ---------------- MFMA flash attention v11: split-K x4, 32 KB LDS ----------------
__global__ __launch_bounds__(256) void attn_mfma(
    const short* __restrict__ Qh_g, const short* __restrict__ Kh_g,
    const short* __restrict__ Vth_g,
    short* __restrict__ op0, float* __restrict__ l0g)
{
    __shared__ short Ksh[4096];          // [key][d] swizzled, 8 KB
    __shared__ short Vsh[4096];          // [d][s] swizzled, 8 KB
    __shared__ short Ph[4][2][1024];     // [wave][qfrag][16x64 swizzled], 16 KB

    const int tid  = threadIdx.x;
    const int lane = tid & 63;
    const int w    = tid >> 6;
    const int quad = lane >> 4;
    const int l15  = lane & 15;

    const int bh    = blockIdx.x & 31;        // XCD-local head
    const int sk    = (blockIdx.x >> 5) & 3;  // K-split quarter
    const int qtile = blockIdx.x >> 7;        // 0..15
    const int q0    = qtile * 128 + w * 32;
    const size_t kvb = (size_t)bh * SEQ * DHEAD;

    bf16x8 ones;
    #pragma unroll
    for (int j = 0; j < 8; ++j) ones[j] = (short)0x3f80;   // bf16 1.0

    bf16x8 qA[2], qB[2];
    {
        const size_t qrA = kvb + (size_t)(q0 + l15) * DHEAD;
        const size_t qrB = kvb + (size_t)(q0 + 16 + l15) * DHEAD;
        qA[0] = *(const bf16x8*)(Qh_g + qrA + quad * 8);
        qA[1] = *(const bf16x8*)(Qh_g + qrA + 32 + quad * 8);
        qB[0] = *(const bf16x8*)(Qh_g + qrB + quad * 8);
        qB[1] = *(const bf16x8*)(Qh_g + qrB + 32 + quad * 8);
    }

    const bool isv = (w >= 2);
    short* dst = isv ? Vsh : Ksh;
    int srow[4], spos[4];
    #pragma unroll
    for (int j = 0; j < 4; ++j) {
        const int c = (w & 1) * 256 + j * 64 + lane;
        srow[j] = c >> 3;
        spos[j] = (c & 7) ^ (srow[j] & 7);
    }

    f32x4 oA[4] = {}, oB[4] = {};
    f32x4 lAv = {}, lBv = {};

    const int kb0 = sk * (SEQ / 4), kb1 = kb0 + SEQ / 4;   // 8 iters
    for (int kb = kb0; kb < kb1; kb += 64) {
        __syncthreads();
        {
            const short* src = isv ? (Vth_g + kvb + kb) : (Kh_g + kvb + (size_t)kb * DHEAD);
            #pragma unroll
            for (int j = 0; j < 4; ++j) {
                const short* g = src + (isv ? ((size_t)srow[j] * SEQ + spos[j] * 8)
                                            : ((size_t)srow[j] * DHEAD + spos[j] * 8));
                async_ld16(g, dst + ((w & 1) * 256 + j * 64) * 8);
            }
        }
        __syncthreads();

        // ---- S^T = K Q^T for both q-fragments (K frags read once) ----
        #pragma unroll
        for (int mf = 0; mf < 4; ++mf) {
            const int row = mf * 16 + l15;
            const int sw = row & 7;
            bf16x8 kh0 = *(const bf16x8*)(Ksh + row * 64 + ((quad ^ sw) * 8));
            bf16x8 kh1 = *(const bf16x8*)(Ksh + row * 64 + (((4 + quad) ^ sw) * 8));
            f32x4 cA = {}, cB = {};
            cA = __builtin_amdgcn_mfma_f32_16x16x32_bf16(kh0, qA[0], cA, 0, 0, 0);
            cA = __builtin_amdgcn_mfma_f32_16x16x32_bf16(kh1, qA[1], cA, 0, 0, 0);
            cB = __builtin_amdgcn_mfma_f32_16x16x32_bf16(kh0, qB[0], cB, 0, 0, 0);
            cB = __builtin_amdgcn_mfma_f32_16x16x32_bf16(kh1, qB[1], cB, 0, 0, 0);

            unsigned uA[4], uB[4];
            #pragma unroll
            for (int r = 0; r < 4; ++r) {
                union { float f; unsigned u; } p;
                p.f = __builtin_amdgcn_exp2f(cA[r]);
                uA[r] = p.u;
                p.f = __builtin_amdgcn_exp2f(cB[r]);
                uB[r] = p.u;
            }
            uint2 pkA, pkB;
            pkA.x = __builtin_amdgcn_perm(uA[1], uA[0], 0x07060302u);
            pkA.y = __builtin_amdgcn_perm(uA[3], uA[2], 0x07060302u);
            pkB.x = __builtin_amdgcn_perm(uB[1], uB[0], 0x07060302u);
            pkB.y = __builtin_amdgcn_perm(uB[3], uB[2], 0x07060302u);
            const int pc = (mf * 2 + (quad >> 1)) ^ (l15 & 7);
            const int paddr = l15 * 64 + pc * 8 + (quad & 1) * 4;
            *(uint2*)(&Ph[w][0][paddr]) = pkA;
            *(uint2*)(&Ph[w][1][paddr]) = pkB;
        }
        // wave-private LDS: in-order within wave, no barrier needed

        const int psw = l15 & 7;
        bf16x8 pA0 = *(const bf16x8*)(&Ph[w][0][l15 * 64 + ((quad ^ psw) * 8)]);
        bf16x8 pA1 = *(const bf16x8*)(&Ph[w][0][l15 * 64 + (((4 + quad) ^ psw) * 8)]);
        bf16x8 pB0 = *(const bf16x8*)(&Ph[w][1][l15 * 64 + ((quad ^ psw) * 8)]);
        bf16x8 pB1 = *(const bf16x8*)(&Ph[w][1][l15 * 64 + (((4 + quad) ^ psw) * 8)]);

        // ---- l += P * ones (row-aligned with O) ----
        lAv = __builtin_amdgcn_mfma_f32_16x16x32_bf16(pA0, ones, lAv, 0, 0, 0);
        lAv = __builtin_amdgcn_mfma_f32_16x16x32_bf16(pA1, ones, lAv, 0, 0, 0);
        lBv = __builtin_amdgcn_mfma_f32_16x16x32_bf16(pB0, ones, lBv, 0, 0, 0);
        lBv = __builtin_amdgcn_mfma_f32_16x16x32_bf16(pB1, ones, lBv, 0, 0, 0);

        // ---- O += P V for both fragments (V frags read once) ----
        #pragma unroll
        for (int nf = 0; nf < 4; ++nf) {
            const int row = nf * 16 + l15;
            const int sw = row & 7;
            bf16x8 vh0 = *(const bf16x8*)(Vsh + row * 64 + ((quad ^ sw) * 8));
            bf16x8 vh1 = *(const bf16x8*)(Vsh + row * 64 + (((4 + quad) ^ sw) * 8));
            f32x4 cA = oA[nf], cB = oB[nf];
            cA = __builtin_amdgcn_mfma_f32_16x16x32_bf16(pA0, vh0, cA, 0, 0, 0);
            cA = __builtin_amdgcn_mfma_f32_16x16x32_bf16(pA1, vh1, cA, 0, 0, 0);
            cB = __builtin_amdgcn_mfma_f32_16x16x32_bf16(pB0, vh0, cB, 0, 0, 0);
            cB = __builtin_amdgcn_mfma_f32_16x16x32_bf16(pB1, vh1, cB, 0, 0, 0);
            oA[nf] = cA; oB[nf] = cB;
        }
    }

    // ---- epilogue: bf16 unnormalized partial O + fp32 partial l ----
    short* op = op0 + (size_t)sk * 4194304;       // partials 8 MB apart
    float* lg = l0g + sk * 65536;
    const int b = bh >> 4, hh = bh & 15;
    #pragma unroll
    for (int r = 0; r < 4; ++r) {
        const int qa = q0 + quad * 4 + r;
        if (l15 == 0) {
            lg[bh * SEQ + qa] = lAv[r];
            lg[bh * SEQ + qa + 16] = lBv[r];
        }
    }
    #pragma unroll
    for (int nf = 0; nf < 4; ++nf) {
        #pragma unroll
        for (int r = 0; r < 4; ++r) {
            const int qa = q0 + quad * 4 + r;
            const int d = nf * 16 + l15;
            op[(size_t)(b * SEQ + qa) * DMODEL + hh * DHEAD + d] = f2bf(oA[nf][r]);
            op[(size_t)(b * SEQ + qa + 16) * DMODEL + hh * DHEAD + d] = f2bf(oB[nf][r]);
        }
    }
}

// ---------------- combine: aoh = bf16(sum4(O)/sum4(l)), bf16 inputs ----------------
__global__ __launch_bounds__(256) void combine_o(
    const short* __restrict__ op0, const float* __restrict__ l0g,
    short* __restrict__ aoh)
{
    const int i = blockIdx.x * 256 + threadIdx.x;   // 8 elems each; grid 2048
    const size_t e = (size_t)i * 8;
    const int qg = (int)(e >> 10);
    const int col = (int)(e & 1023);
    const int b = qg >> 11;
    const int q = qg & (SEQ - 1);
    const int bhq = (b * NHEADS + (col >> 6)) * SEQ + q;
    const float inv = 1.0f / (l0g[bhq] + l0g[bhq + 65536] +
                              l0g[bhq + 2 * 65536] + l0g[bhq + 3 * 65536]);

    bf16x8 a0 = *((const bf16x8*)op0 + i);
    bf16x8 a1 = *((const bf16x8*)(op0 + 4194304) + i);
    bf16x8 a2 = *((const bf16x8*)(op0 + 2 * 4194304) + i);
    bf16x8 a3 = *((const bf16x8*)(op0 + 3 * 4194304) + i);
    bf16x8 H;
    #pragma unroll
    for (int j = 0; j < 8; ++j)
        H[j] = f2bf((bf2f(a0[j]) + bf2f(a1[j]) + bf2f(a2[j]) + bf2f(a3[j])) * inv);
    *((bf16x8*)aoh + i) = H;
}

// ---------------- launch ----------------
extern "C" void kernel_launch(void* const* d_in, const int* in_sizes, int n_in,
                              void* d_out, int out_size, void* d_ws, size_t ws_size,
                              hipStream_t stream) {
    const float* x  = (const float*)d_in[0];
    // d_in[1] = pH : softmax shift-invariant, ignored
    const float* Wq = (const float*)d_in[2];
    const float* bq = (const float*)d_in[3];
    const float* Wk = (const float*)d_in[4];
    const float* bk = (const float*)d_in[5];
    const float* Wv = (const float*)d_in[6];
    const float* bv = (const float*)d_in[7];
    const float* Wo = (const float*)d_in[8];
    const float* bo = (const float*)d_in[9];
    float* out = (float*)d_out;

    char* ws = (char*)d_ws;
    const size_t MB = 1024 * 1024;
    short* qh  = (short*)(ws + 0 * MB);      // 8 MB
    short* kh  = (short*)(ws + 16 * MB);     // 8 MB
    short* vth = (short*)(ws + 32 * MB);     // 8 MB
    short* aoh = (short*)(ws + 48 * MB);     // 8 MB
    short* op0 = (short*)(ws + 56 * MB);     // 4x8 MB bf16 partials at 56/64/72/80
                                             //   (64=xhi, 80=wqkv: dead after QKV)
    short* xhi = (short*)(ws + 64 * MB);     // 8 MB (dead after QKV GEMM)
    short* wqkv_hi = (short*)(ws + 80 * MB); // 6 MB (dead after QKV GEMM)
    float* l0g = (float*)(ws + 88 * MB);     // 4x256 KB partial l
    short* wto_hi  = (short*)(ws + 92 * MB); // 2 MB

    dim3 blk(256);

    hipLaunchKernelGGL(prep, dim3(2048 + 1024), blk, 0, stream,
                       x, xhi, Wq, Wk, Wv, Wo, wqkv_hi, wto_hi);

    const float qscale = 0.125f * 1.44269504088896f;   // fold 1/sqrt(dh)*log2(e)
    hipLaunchKernelGGL(mfma_gemm, dim3(3072 / 128, MROWS / 128), blk, 0, stream,
                       xhi, wqkv_hi, bq, bk, bv, qh, kh, vth, qscale);

    hipLaunchKernelGGL(attn_mfma, dim3(BATCH * NHEADS * (SEQ / 128) * 4), blk, 0, stream,
                       qh, kh, vth, op0, l0g);

    hipLaunchKernelGGL(combine_o, dim3(MROWS * DMODEL / 8 / 256), blk, 0, stream,
                       op0, l0g, aoh);

    hipLaunchKernelGGL(ogemm, dim3(1024 / 128, MROWS / 64), blk, 0, stream,
                       aoh, wto_hi, bo, out);
}

// Round 14
// 198.697 us; speedup vs baseline: 1.0768x; 1.0340x over previous
//
#include <hip/hip_runtime.h>
#include <hip/hip_bf16.h>
#include <math.h>

// Problem constants
#define BATCH 2
#define SEQ   2048
#define DMODEL 1024
#define NHEADS 16
#define DHEAD 64
#define MROWS (BATCH*SEQ)   // 4096

typedef __attribute__((ext_vector_type(8))) short bf16x8;
typedef __attribute__((ext_vector_type(4))) short bf16x4;
typedef __attribute__((ext_vector_type(4))) float f32x4;

__device__ __forceinline__ short f2bf(float f) {   // RNE float->bf16
    union { float f; unsigned u; } c; c.f = f;
    unsigned r = (c.u + 0x7fffu + ((c.u >> 16) & 1u)) >> 16;
    return (short)r;
}
__device__ __forceinline__ float bf2f(short h) {
    union { unsigned u; float f; } c; c.u = ((unsigned)(unsigned short)h) << 16;
    return c.f;
}

__device__ __forceinline__ void async_ld16(const void* g, void* l) {
    __builtin_amdgcn_global_load_lds(
        (const __attribute__((address_space(1))) unsigned*)g,
        (__attribute__((address_space(3))) unsigned*)l, 16, 0, 0);
}

// ---------------- fused prep: convert x -> bf16 AND transpose 4 weights ----------------
__global__ __launch_bounds__(256) void prep(
    const float* __restrict__ x, short* __restrict__ xhi,
    const float* __restrict__ W0, const float* __restrict__ W1,
    const float* __restrict__ W2, const float* __restrict__ W3,
    short* __restrict__ oqkv, short* __restrict__ oo)
{
    __shared__ float T[64][65];
    const int tid = threadIdx.x;
    if (blockIdx.x < 2048) {
        const int i = blockIdx.x * 256 + tid;
        const float4* p = (const float4*)x + (size_t)i * 2;
        float4 a = p[0], b = p[1];
        float v[8] = {a.x, a.y, a.z, a.w, b.x, b.y, b.z, b.w};
        bf16x8 H;
        #pragma unroll
        for (int j = 0; j < 8; ++j) H[j] = f2bf(v[j]);
        *((bf16x8*)xhi + i) = H;
        return;
    }
    const int bi = blockIdx.x - 2048;
    const int z = bi >> 8;
    const int t = bi & 255;
    const float* W = (z == 0) ? W0 : (z == 1) ? W1 : (z == 2) ? W2 : W3;
    short* out = (z < 3) ? (oqkv + (size_t)z * 1024 * 1024) : oo;
    const int n0 = (t & 15) * 64, k0 = (t >> 4) * 64;
    #pragma unroll
    for (int i = 0; i < 16; ++i) {
        const int idx = tid + i * 256;
        const int r = idx >> 6, c = idx & 63;
        T[r][c] = W[(size_t)(k0 + r) * DMODEL + n0 + c];
    }
    __syncthreads();
    #pragma unroll
    for (int i = 0; i < 4; ++i) {
        const int idx = tid + i * 256;
        const int r = idx >> 4, g = idx & 15;
        bf16x4 H;
        #pragma unroll
        for (int j = 0; j < 4; ++j)
            H[j] = f2bf(T[g * 4 + j][r]);
        *(bf16x4*)(out + (size_t)(n0 + r) * DMODEL + k0 + g * 4) = H;
    }
}

// ---------------- QKV GEMM: 64x128 tile, grid (24,64)=1536 blocks (6/CU) ----------------
// q/k bf16 [B,H,S,64], v bf16 transposed [B,H,64,S]; LDS-scratch coalesced epilogue.
__global__ __launch_bounds__(256) void qkv_gemm(
    const short* __restrict__ Ahi, const short* __restrict__ Bthi,
    const float* __restrict__ b0, const float* __restrict__ b1, const float* __restrict__ b2,
    short* __restrict__ oqh, short* __restrict__ okh, short* __restrict__ ovh,
    float qscale)
{
    __shared__ short Ah[64 * 64], Bh[128 * 64];   // 8 KB + 16 KB

    const int tid  = threadIdx.x;
    const int lane = tid & 63;
    const int w    = tid >> 6;
    const int quad = lane >> 4;
    const int l15  = lane & 15;
    const int wr   = w >> 1, wc = w & 1;
    const int m0   = blockIdx.y * 64;
    const int n0   = blockIdx.x * 128;
    const int K    = DMODEL;

    f32x4 acc[2][4] = {};

    for (int k0 = 0; k0 < K; k0 += 64) {
        __syncthreads();
        // unified staging: 1536 chunks (A:512, B:1024); 6 wave-uniform calls/wave
        #pragma unroll
        for (int j = 0; j < 6; ++j) {
            const int base = w * 384 + j * 64;   // A/B split at 512 (wave-uniform)
            const int c = base + lane;
            if (base < 512) {
                const int row = c >> 3, pos = (c & 7) ^ (row & 7);
                async_ld16(Ahi + (size_t)(m0 + row) * K + k0 + pos * 8, Ah + base * 8);
            } else {
                const int cb = c - 512;
                const int row = cb >> 3, pos = (cb & 7) ^ (row & 7);
                async_ld16(Bthi + (size_t)(n0 + row) * K + k0 + pos * 8, Bh + (base - 512) * 8);
            }
        }
        __syncthreads();

        #pragma unroll
        for (int s = 0; s < 2; ++s) {
            bf16x8 afh[2], bfh[4];
            #pragma unroll
            for (int mi = 0; mi < 2; ++mi) {
                const int row = wr * 32 + mi * 16 + l15;
                const int pos = (s * 4 + quad) ^ (row & 7);
                afh[mi] = *(const bf16x8*)(Ah + row * 64 + pos * 8);
            }
            #pragma unroll
            for (int ni = 0; ni < 4; ++ni) {
                const int row = wc * 64 + ni * 16 + l15;
                const int pos = (s * 4 + quad) ^ (row & 7);
                bfh[ni] = *(const bf16x8*)(Bh + row * 64 + pos * 8);
            }
            #pragma unroll
            for (int mi = 0; mi < 2; ++mi)
                #pragma unroll
                for (int ni = 0; ni < 4; ++ni)
                    acc[mi][ni] = __builtin_amdgcn_mfma_f32_16x16x32_bf16(
                        afh[mi], bfh[ni], acc[mi][ni], 0, 0, 0);
        }
    }

    const int nbase = n0 + wc * 64;              // one head per wave
    const int which = nbase >> 10;               // 0=q, 1=k, 2=v (wave-uniform)
    const int hh = (nbase & 1023) >> 6;
    const int mb = m0 + wr * 32;
    const int b = mb >> 11, sbase = mb & (SEQ - 1);
    __syncthreads();   // all waves done reading Ah/Bh; reuse as scratch
    short* scr = (w < 2) ? (Ah + w * 2048) : (Bh + (w - 2) * 2048);  // 4 KB/wave

    if (which < 2) {
        const float* bias = which ? b1 : b0;
        short* dstp = which ? okh : oqh;
        const float scl = which ? 1.0f : qscale;
        // scratch[s][d] 32x64, XOR-8 chunk swizzle
        #pragma unroll
        for (int mi = 0; mi < 2; ++mi)
            #pragma unroll
            for (int ni = 0; ni < 4; ++ni)
                #pragma unroll
                for (int r = 0; r < 4; ++r) {
                    const int sloc = mi * 16 + quad * 4 + r;
                    const int dloc = ni * 16 + l15;
                    const int nn = (nbase + ni * 16 + l15) & 1023;
                    scr[sloc * 64 + (((dloc >> 3) ^ (sloc & 7)) * 8) + (dloc & 7)] =
                        f2bf((acc[mi][ni][r] + bias[nn]) * scl);
                }
        #pragma unroll
        for (int i = 0; i < 4; ++i) {
            const int sloc = i * 8 + (lane >> 3);
            const int cph = (lane & 7) ^ (sloc & 7);
            bf16x8 row = *(const bf16x8*)(scr + sloc * 64 + cph * 8);
            const int dloc = (lane & 7) * 8;
            *(bf16x8*)(dstp + ((size_t)(b * NHEADS + hh) * SEQ + sbase + sloc) * DHEAD + dloc) = row;
        }
    } else {
        // scratch[d][s] 64x32 (transposed), XOR-4 chunk swizzle
        #pragma unroll
        for (int mi = 0; mi < 2; ++mi)
            #pragma unroll
            for (int ni = 0; ni < 4; ++ni)
                #pragma unroll
                for (int r = 0; r < 4; ++r) {
                    const int sloc = mi * 16 + quad * 4 + r;
                    const int dloc = ni * 16 + l15;
                    const int nn = (nbase + ni * 16 + l15) & 1023;
                    scr[dloc * 32 + (((sloc >> 3) ^ (dloc & 3)) * 8) + (sloc & 7)] =
                        f2bf(acc[mi][ni][r] + b2[nn]);
                }
        #pragma unroll
        for (int i = 0; i < 4; ++i) {
            const int dloc = i * 16 + (lane >> 2);
            const int cph = (lane & 3) ^ (dloc & 3);
            bf16x8 row = *(const bf16x8*)(scr + dloc * 32 + cph * 8);
            const int sg = sbase + (lane & 3) * 8;
            *(bf16x8*)(ovh + ((size_t)(b * NHEADS + hh) * DHEAD + dloc) * SEQ + sg) = row;
        }
    }
}

// ---------------- O-proj GEMM: 64x128 tile, grid 512 (2 blocks/CU) ----------------
__global__ __launch_bounds__(256) void ogemm(
    const short* __restrict__ Ahi, const short* __restrict__ Bthi,
    const float* __restrict__ b0, float* __restrict__ outf)
{
    __shared__ short Ah[64 * 64], Bh[128 * 64];   // 8 KB + 16 KB

    const int tid  = threadIdx.x;
    const int lane = tid & 63;
    const int w    = tid >> 6;
    const int quad = lane >> 4;
    const int l15  = lane & 15;
    const int wr   = w >> 1, wc = w & 1;
    const int m0   = blockIdx.y * 64;
    const int n0   = blockIdx.x * 128;
    const int K    = DMODEL;

    f32x4 acc[2][4] = {};

    for (int k0 = 0; k0 < K; k0 += 64) {
        __syncthreads();
        #pragma unroll
        for (int j = 0; j < 6; ++j) {
            const int base = w * 384 + j * 64;
            const int c = base + lane;
            if (base < 512) {
                const int row = c >> 3, pos = (c & 7) ^ (row & 7);
                async_ld16(Ahi + (size_t)(m0 + row) * K + k0 + pos * 8, Ah + base * 8);
            } else {
                const int cb = c - 512;
                const int row = cb >> 3, pos = (cb & 7) ^ (row & 7);
                async_ld16(Bthi + (size_t)(n0 + row) * K + k0 + pos * 8, Bh + (base - 512) * 8);
            }
        }
        __syncthreads();

        #pragma unroll
        for (int s = 0; s < 2; ++s) {
            bf16x8 afh[2], bfh[4];
            #pragma unroll
            for (int mi = 0; mi < 2; ++mi) {
                const int row = wr * 32 + mi * 16 + l15;
                const int pos = (s * 4 + quad) ^ (row & 7);
                afh[mi] = *(const bf16x8*)(Ah + row * 64 + pos * 8);
            }
            #pragma unroll
            for (int ni = 0; ni < 4; ++ni) {
                const int row = wc * 64 + ni * 16 + l15;
                const int pos = (s * 4 + quad) ^ (row & 7);
                bfh[ni] = *(const bf16x8*)(Bh + row * 64 + pos * 8);
            }
            #pragma unroll
            for (int mi = 0; mi < 2; ++mi)
                #pragma unroll
                for (int ni = 0; ni < 4; ++ni)
                    acc[mi][ni] = __builtin_amdgcn_mfma_f32_16x16x32_bf16(
                        afh[mi], bfh[ni], acc[mi][ni], 0, 0, 0);
        }
    }

    #pragma unroll
    for (int mi = 0; mi < 2; ++mi)
        #pragma unroll
        for (int ni = 0; ni < 4; ++ni)
            #pragma unroll
            for (int r = 0; r < 4; ++r) {
                const int m = m0 + wr * 32 + mi * 16 + quad * 4 + r;
                const int nn = n0 + wc * 64 + ni * 16 + l15;
                outf[(size_t)m * DMODEL + nn] = acc[mi][ni][r] + b0[nn];
            }
}

// ---------------- MFMA flash attention v11: split-K x4, 32 KB LDS ----------------
__global__ __launch_bounds__(256) void attn_mfma(
    const short* __restrict__ Qh_g, const short* __restrict__ Kh_g,
    const short* __restrict__ Vth_g,
    short* __restrict__ op0, float* __restrict__ l0g)
{
    __shared__ short Ksh[4096];          // [key][d] swizzled, 8 KB
    __shared__ short Vsh[4096];          // [d][s] swizzled, 8 KB
    __shared__ short Ph[4][2][1024];     // [wave][qfrag][16x64 swizzled], 16 KB

    const int tid  = threadIdx.x;
    const int lane = tid & 63;
    const int w    = tid >> 6;
    const int quad = lane >> 4;
    const int l15  = lane & 15;

    const int bh    = blockIdx.x & 31;        // XCD-local head
    const int sk    = (blockIdx.x >> 5) & 3;  // K-split quarter
    const int qtile = blockIdx.x >> 7;        // 0..15
    const int q0    = qtile * 128 + w * 32;
    const size_t kvb = (size_t)bh * SEQ * DHEAD;

    bf16x8 ones;
    #pragma unroll
    for (int j = 0; j < 8; ++j) ones[j] = (short)0x3f80;   // bf16 1.0

    bf16x8 qA[2], qB[2];
    {
        const size_t qrA = kvb + (size_t)(q0 + l15) * DHEAD;
        const size_t qrB = kvb + (size_t)(q0 + 16 + l15) * DHEAD;
        qA[0] = *(const bf16x8*)(Qh_g + qrA + quad * 8);
        qA[1] = *(const bf16x8*)(Qh_g + qrA + 32 + quad * 8);
        qB[0] = *(const bf16x8*)(Qh_g + qrB + quad * 8);
        qB[1] = *(const bf16x8*)(Qh_g + qrB + 32 + quad * 8);
    }

    const bool isv = (w >= 2);
    short* dst = isv ? Vsh : Ksh;
    int srow[4], spos[4];
    #pragma unroll
    for (int j = 0; j < 4; ++j) {
        const int c = (w & 1) * 256 + j * 64 + lane;
        srow[j] = c >> 3;
        spos[j] = (c & 7) ^ (srow[j] & 7);
    }

    f32x4 oA[4] = {}, oB[4] = {};
    f32x4 lAv = {}, lBv = {};

    const int kb0 = sk * (SEQ / 4), kb1 = kb0 + SEQ / 4;   // 8 iters
    for (int kb = kb0; kb < kb1; kb += 64) {
        __syncthreads();
        {
            const short* src = isv ? (Vth_g + kvb + kb) : (Kh_g + kvb + (size_t)kb * DHEAD);
            #pragma unroll
            for (int j = 0; j < 4; ++j) {
                const short* g = src + (isv ? ((size_t)srow[j] * SEQ + spos[j] * 8)
                                            : ((size_t)srow[j] * DHEAD + spos[j] * 8));
                async_ld16(g, dst + ((w & 1) * 256 + j * 64) * 8);
            }
        }
        __syncthreads();

        // ---- S^T = K Q^T for both q-fragments (K frags read once) ----
        #pragma unroll
        for (int mf = 0; mf < 4; ++mf) {
            const int row = mf * 16 + l15;
            const int sw = row & 7;
            bf16x8 kh0 = *(const bf16x8*)(Ksh + row * 64 + ((quad ^ sw) * 8));
            bf16x8 kh1 = *(const bf16x8*)(Ksh + row * 64 + (((4 + quad) ^ sw) * 8));
            f32x4 cA = {}, cB = {};
            cA = __builtin_amdgcn_mfma_f32_16x16x32_bf16(kh0, qA[0], cA, 0, 0, 0);
            cA = __builtin_amdgcn_mfma_f32_16x16x32_bf16(kh1, qA[1], cA, 0, 0, 0);
            cB = __builtin_amdgcn_mfma_f32_16x16x32_bf16(kh0, qB[0], cB, 0, 0, 0);
            cB = __builtin_amdgcn_mfma_f32_16x16x32_bf16(kh1, qB[1], cB, 0, 0, 0);

            unsigned uA[4], uB[4];
            #pragma unroll
            for (int r = 0; r < 4; ++r) {
                union { float f; unsigned u; } p;
                p.f = __builtin_amdgcn_exp2f(cA[r]);
                uA[r] = p.u;
                p.f = __builtin_amdgcn_exp2f(cB[r]);
                uB[r] = p.u;
            }
            uint2 pkA, pkB;
            pkA.x = __builtin_amdgcn_perm(uA[1], uA[0], 0x07060302u);
            pkA.y = __builtin_amdgcn_perm(uA[3], uA[2], 0x07060302u);
            pkB.x = __builtin_amdgcn_perm(uB[1], uB[0], 0x07060302u);
            pkB.y = __builtin_amdgcn_perm(uB[3], uB[2], 0x07060302u);
            const int pc = (mf * 2 + (quad >> 1)) ^ (l15 & 7);
            const int paddr = l15 * 64 + pc * 8 + (quad & 1) * 4;
            *(uint2*)(&Ph[w][0][paddr]) = pkA;
            *(uint2*)(&Ph[w][1][paddr]) = pkB;
        }
        // wave-private LDS: in-order within wave, no barrier needed

        const int psw = l15 & 7;
        bf16x8 pA0 = *(const bf16x8*)(&Ph[w][0][l15 * 64 + ((quad ^ psw) * 8)]);
        bf16x8 pA1 = *(const bf16x8*)(&Ph[w][0][l15 * 64 + (((4 + quad) ^ psw) * 8)]);
        bf16x8 pB0 = *(const bf16x8*)(&Ph[w][1][l15 * 64 + ((quad ^ psw) * 8)]);
        bf16x8 pB1 = *(const bf16x8*)(&Ph[w][1][l15 * 64 + (((4 + quad) ^ psw) * 8)]);

        // ---- l += P * ones (row-aligned with O) ----
        lAv = __builtin_amdgcn_mfma_f32_16x16x32_bf16(pA0, ones, lAv, 0, 0, 0);
        lAv = __builtin_amdgcn_mfma_f32_16x16x32_bf16(pA1, ones, lAv, 0, 0, 0);
        lBv = __builtin_amdgcn_mfma_f32_16x16x32_bf16(pB0, ones, lBv, 0, 0, 0);
        lBv = __builtin_amdgcn_mfma_f32_16x16x32_bf16(pB1, ones, lBv, 0, 0, 0);

        // ---- O += P V for both fragments (V frags read once) ----
        #pragma unroll
        for (int nf = 0; nf < 4; ++nf) {
            const int row = nf * 16 + l15;
            const int sw = row & 7;
            bf16x8 vh0 = *(const bf16x8*)(Vsh + row * 64 + ((quad ^ sw) * 8));
            bf16x8 vh1 = *(const bf16x8*)(Vsh + row * 64 + (((4 + quad) ^ sw) * 8));
            f32x4 cA = oA[nf], cB = oB[nf];
            cA = __builtin_amdgcn_mfma_f32_16x16x32_bf16(pA0, vh0, cA, 0, 0, 0);
            cA = __builtin_amdgcn_mfma_f32_16x16x32_bf16(pA1, vh1, cA, 0, 0, 0);
            cB = __builtin_amdgcn_mfma_f32_16x16x32_bf16(pB0, vh0, cB, 0, 0, 0);
            cB = __builtin_amdgcn_mfma_f32_16x16x32_bf16(pB1, vh1, cB, 0, 0, 0);
            oA[nf] = cA; oB[nf] = cB;
        }
    }

    // ---- epilogue: bf16 unnormalized partial O + fp32 partial l ----
    short* op = op0 + (size_t)sk * 4194304;       // partials 8 MB apart
    float* lg = l0g + sk * 65536;
    const int b = bh >> 4, hh = bh & 15;
    #pragma unroll
    for (int r = 0; r < 4; ++r) {
        const int qa = q0 + quad * 4 + r;
        if (l15 == 0) {
            lg[bh * SEQ + qa] = lAv[r];
            lg[bh * SEQ + qa + 16] = lBv[r];
        }
    }
    #pragma unroll
    for (int nf = 0; nf < 4; ++nf) {
        #pragma unroll
        for (int r = 0; r < 4; ++r) {
            const int qa = q0 + quad * 4 + r;
            const int d = nf * 16 + l15;
            op[(size_t)(b * SEQ + qa) * DMODEL + hh * DHEAD + d] = f2bf(oA[nf][r]);
            op[(size_t)(b * SEQ + qa + 16) * DMODEL + hh * DHEAD + d] = f2bf(oB[nf][r]);
        }
    }
}

// ---------------- combine: aoh = bf16(sum4(O)/sum4(l)), bf16 inputs ----------------
__global__ __launch_bounds__(256) void combine_o(
    const short* __restrict__ op0, const float* __restrict__ l0g,
    short* __restrict__ aoh)
{
    const int i = blockIdx.x * 256 + threadIdx.x;   // 8 elems each; grid 2048
    const size_t e = (size_t)i * 8;
    const int qg = (int)(e >> 10);
    const int col = (int)(e & 1023);
    const int b = qg >> 11;
    const int q = qg & (SEQ - 1);
    const int bhq = (b * NHEADS + (col >> 6)) * SEQ + q;
    const float inv = 1.0f / (l0g[bhq] + l0g[bhq + 65536] +
                              l0g[bhq + 2 * 65536] + l0g[bhq + 3 * 65536]);

    bf16x8 a0 = *((const bf16x8*)op0 + i);
    bf16x8 a1 = *((const bf16x8*)(op0 + 4194304) + i);
    bf16x8 a2 = *((const bf16x8*)(op0 + 2 * 4194304) + i);
    bf16x8 a3 = *((const bf16x8*)(op0 + 3 * 4194304) + i);
    bf16x8 H;
    #pragma unroll
    for (int j = 0; j < 8; ++j)
        H[j] = f2bf((bf2f(a0[j]) + bf2f(a1[j]) + bf2f(a2[j]) + bf2f(a3[j])) * inv);
    *((bf16x8*)aoh + i) = H;
}

// ---------------- launch ----------------
extern "C" void kernel_launch(void* const* d_in, const int* in_sizes, int n_in,
                              void* d_out, int out_size, void* d_ws, size_t ws_size,
                              hipStream_t stream) {
    const float* x  = (const float*)d_in[0];
    // d_in[1] = pH : softmax shift-invariant, ignored
    const float* Wq = (const float*)d_in[2];
    const float* bq = (const float*)d_in[3];
    const float* Wk = (const float*)d_in[4];
    const float* bk = (const float*)d_in[5];
    const float* Wv = (const float*)d_in[6];
    const float* bv = (const float*)d_in[7];
    const float* Wo = (const float*)d_in[8];
    const float* bo = (const float*)d_in[9];
    float* out = (float*)d_out;

    char* ws = (char*)d_ws;
    const size_t MB = 1024 * 1024;
    short* qh  = (short*)(ws + 0 * MB);      // 8 MB
    short* kh  = (short*)(ws + 16 * MB);     // 8 MB
    short* vth = (short*)(ws + 32 * MB);     // 8 MB
    short* aoh = (short*)(ws + 48 * MB);     // 8 MB
    short* op0 = (short*)(ws + 56 * MB);     // 4x8 MB bf16 partials at 56/64/72/80
                                             //   (64=xhi, 80=wqkv: dead after QKV)
    short* xhi = (short*)(ws + 64 * MB);     // 8 MB (dead after QKV GEMM)
    short* wqkv_hi = (short*)(ws + 80 * MB); // 6 MB (dead after QKV GEMM)
    float* l0g = (float*)(ws + 88 * MB);     // 4x256 KB partial l
    short* wto_hi  = (short*)(ws + 92 * MB); // 2 MB

    dim3 blk(256);

    hipLaunchKernelGGL(prep, dim3(2048 + 1024), blk, 0, stream,
                       x, xhi, Wq, Wk, Wv, Wo, wqkv_hi, wto_hi);

    const float qscale = 0.125f * 1.44269504088896f;   // fold 1/sqrt(dh)*log2(e)
    hipLaunchKernelGGL(qkv_gemm, dim3(3072 / 128, MROWS / 64), blk, 0, stream,
                       xhi, wqkv_hi, bq, bk, bv, qh, kh, vth, qscale);

    hipLaunchKernelGGL(attn_mfma, dim3(BATCH * NHEADS * (SEQ / 128) * 4), blk, 0, stream,
                       qh, kh, vth, op0, l0g);

    hipLaunchKernelGGL(combine_o, dim3(MROWS * DMODEL / 8 / 256), blk, 0, stream,
                       op0, l0g, aoh);

    hipLaunchKernelGGL(ogemm, dim3(1024 / 128, MROWS / 64), blk, 0, stream,
                       aoh, wto_hi, bo, out);
}

// Round 15
// 196.445 us; speedup vs baseline: 1.0891x; 1.0115x over previous
//
#include <hip/hip_runtime.h>
#include <hip/hip_bf16.h>
#include <math.h>

// Problem constants
#define BATCH 2
#define SEQ   2048
#define DMODEL 1024
#define NHEADS 16
#define DHEAD 64
#define MROWS (BATCH*SEQ)   // 4096

typedef __attribute__((ext_vector_type(8))) short bf16x8;
typedef __attribute__((ext_vector_type(4))) short bf16x4;
typedef __attribute__((ext_vector_type(4))) float f32x4;

__device__ __forceinline__ short f2bf(float f) {   // RNE float->bf16
    union { float f; unsigned u; } c; c.f = f;
    unsigned r = (c.u + 0x7fffu + ((c.u >> 16) & 1u)) >> 16;
    return (short)r;
}
__device__ __forceinline__ float bf2f(short h) {
    union { unsigned u; float f; } c; c.u = ((unsigned)(unsigned short)h) << 16;
    return c.f;
}

__device__ __forceinline__ void async_ld16(const void* g, void* l) {
    __builtin_amdgcn_global_load_lds(
        (const __attribute__((address_space(1))) unsigned*)g,
        (__attribute__((address_space(3))) unsigned*)l, 16, 0, 0);
}

// ---------------- fused prep: convert x -> bf16 AND transpose 4 weights ----------------
__global__ __launch_bounds__(256) void prep(
    const float* __restrict__ x, short* __restrict__ xhi,
    const float* __restrict__ W0, const float* __restrict__ W1,
    const float* __restrict__ W2, const float* __restrict__ W3,
    short* __restrict__ oqkv, short* __restrict__ oo)
{
    __shared__ float T[64][65];
    const int tid = threadIdx.x;
    if (blockIdx.x < 2048) {
        const int i = blockIdx.x * 256 + tid;
        const float4* p = (const float4*)x + (size_t)i * 2;
        float4 a = p[0], b = p[1];
        float v[8] = {a.x, a.y, a.z, a.w, b.x, b.y, b.z, b.w};
        bf16x8 H;
        #pragma unroll
        for (int j = 0; j < 8; ++j) H[j] = f2bf(v[j]);
        *((bf16x8*)xhi + i) = H;
        return;
    }
    const int bi = blockIdx.x - 2048;
    const int z = bi >> 8;
    const int t = bi & 255;
    const float* W = (z == 0) ? W0 : (z == 1) ? W1 : (z == 2) ? W2 : W3;
    short* out = (z < 3) ? (oqkv + (size_t)z * 1024 * 1024) : oo;
    const int n0 = (t & 15) * 64, k0 = (t >> 4) * 64;
    #pragma unroll
    for (int i = 0; i < 16; ++i) {
        const int idx = tid + i * 256;
        const int r = idx >> 6, c = idx & 63;
        T[r][c] = W[(size_t)(k0 + r) * DMODEL + n0 + c];
    }
    __syncthreads();
    #pragma unroll
    for (int i = 0; i < 4; ++i) {
        const int idx = tid + i * 256;
        const int r = idx >> 4, g = idx & 15;
        bf16x4 H;
        #pragma unroll
        for (int j = 0; j < 4; ++j)
            H[j] = f2bf(T[g * 4 + j][r]);
        *(bf16x4*)(out + (size_t)(n0 + r) * DMODEL + k0 + g * 4) = H;
    }
}

// ---------------- QKV GEMM: 64x128 tile, grid (24,64)=1536 blocks (6/CU) ----------------
__global__ __launch_bounds__(256) void qkv_gemm(
    const short* __restrict__ Ahi, const short* __restrict__ Bthi,
    const float* __restrict__ b0, const float* __restrict__ b1, const float* __restrict__ b2,
    short* __restrict__ oqh, short* __restrict__ okh, short* __restrict__ ovh,
    float qscale)
{
    __shared__ short Ah[64 * 64], Bh[128 * 64];   // 8 KB + 16 KB

    const int tid  = threadIdx.x;
    const int lane = tid & 63;
    const int w    = tid >> 6;
    const int quad = lane >> 4;
    const int l15  = lane & 15;
    const int wr   = w >> 1, wc = w & 1;
    const int m0   = blockIdx.y * 64;
    const int n0   = blockIdx.x * 128;
    const int K    = DMODEL;

    f32x4 acc[2][4] = {};

    for (int k0 = 0; k0 < K; k0 += 64) {
        __syncthreads();
        #pragma unroll
        for (int j = 0; j < 6; ++j) {
            const int base = w * 384 + j * 64;   // A/B split at 512 (wave-uniform)
            const int c = base + lane;
            if (base < 512) {
                const int row = c >> 3, pos = (c & 7) ^ (row & 7);
                async_ld16(Ahi + (size_t)(m0 + row) * K + k0 + pos * 8, Ah + base * 8);
            } else {
                const int cb = c - 512;
                const int row = cb >> 3, pos = (cb & 7) ^ (row & 7);
                async_ld16(Bthi + (size_t)(n0 + row) * K + k0 + pos * 8, Bh + (base - 512) * 8);
            }
        }
        __syncthreads();

        #pragma unroll
        for (int s = 0; s < 2; ++s) {
            bf16x8 afh[2], bfh[4];
            #pragma unroll
            for (int mi = 0; mi < 2; ++mi) {
                const int row = wr * 32 + mi * 16 + l15;
                const int pos = (s * 4 + quad) ^ (row & 7);
                afh[mi] = *(const bf16x8*)(Ah + row * 64 + pos * 8);
            }
            #pragma unroll
            for (int ni = 0; ni < 4; ++ni) {
                const int row = wc * 64 + ni * 16 + l15;
                const int pos = (s * 4 + quad) ^ (row & 7);
                bfh[ni] = *(const bf16x8*)(Bh + row * 64 + pos * 8);
            }
            #pragma unroll
            for (int mi = 0; mi < 2; ++mi)
                #pragma unroll
                for (int ni = 0; ni < 4; ++ni)
                    acc[mi][ni] = __builtin_amdgcn_mfma_f32_16x16x32_bf16(
                        afh[mi], bfh[ni], acc[mi][ni], 0, 0, 0);
        }
    }

    const int nbase = n0 + wc * 64;              // one head per wave
    const int which = nbase >> 10;               // 0=q, 1=k, 2=v (wave-uniform)
    const int hh = (nbase & 1023) >> 6;
    const int mb = m0 + wr * 32;
    const int b = mb >> 11, sbase = mb & (SEQ - 1);
    __syncthreads();   // all waves done reading Ah/Bh; reuse as scratch
    short* scr = (w < 2) ? (Ah + w * 2048) : (Bh + (w - 2) * 2048);  // 4 KB/wave

    if (which < 2) {
        const float* bias = which ? b1 : b0;
        short* dstp = which ? okh : oqh;
        const float scl = which ? 1.0f : qscale;
        #pragma unroll
        for (int mi = 0; mi < 2; ++mi)
            #pragma unroll
            for (int ni = 0; ni < 4; ++ni)
                #pragma unroll
                for (int r = 0; r < 4; ++r) {
                    const int sloc = mi * 16 + quad * 4 + r;
                    const int dloc = ni * 16 + l15;
                    const int nn = (nbase + ni * 16 + l15) & 1023;
                    scr[sloc * 64 + (((dloc >> 3) ^ (sloc & 7)) * 8) + (dloc & 7)] =
                        f2bf((acc[mi][ni][r] + bias[nn]) * scl);
                }
        #pragma unroll
        for (int i = 0; i < 4; ++i) {
            const int sloc = i * 8 + (lane >> 3);
            const int cph = (lane & 7) ^ (sloc & 7);
            bf16x8 row = *(const bf16x8*)(scr + sloc * 64 + cph * 8);
            const int dloc = (lane & 7) * 8;
            *(bf16x8*)(dstp + ((size_t)(b * NHEADS + hh) * SEQ + sbase + sloc) * DHEAD + dloc) = row;
        }
    } else {
        #pragma unroll
        for (int mi = 0; mi < 2; ++mi)
            #pragma unroll
            for (int ni = 0; ni < 4; ++ni)
                #pragma unroll
                for (int r = 0; r < 4; ++r) {
                    const int sloc = mi * 16 + quad * 4 + r;
                    const int dloc = ni * 16 + l15;
                    const int nn = (nbase + ni * 16 + l15) & 1023;
                    scr[dloc * 32 + (((sloc >> 3) ^ (dloc & 3)) * 8) + (sloc & 7)] =
                        f2bf(acc[mi][ni][r] + b2[nn]);
                }
        #pragma unroll
        for (int i = 0; i < 4; ++i) {
            const int dloc = i * 16 + (lane >> 2);
            const int cph = (lane & 3) ^ (dloc & 3);
            bf16x8 row = *(const bf16x8*)(scr + dloc * 32 + cph * 8);
            const int sg = sbase + (lane & 3) * 8;
            *(bf16x8*)(ovh + ((size_t)(b * NHEADS + hh) * DHEAD + dloc) * SEQ + sg) = row;
        }
    }
}

// ---------------- O-proj GEMM: 64x64 tile, grid (16,64)=1024 (4 blocks/CU) ----------------
__global__ __launch_bounds__(256) void ogemm(
    const short* __restrict__ Ahi, const short* __restrict__ Bthi,
    const float* __restrict__ b0, float* __restrict__ outf)
{
    __shared__ short Ah[64 * 64], Bh[64 * 64];   // 8 KB + 8 KB

    const int tid  = threadIdx.x;
    const int lane = tid & 63;
    const int w    = tid >> 6;
    const int quad = lane >> 4;
    const int l15  = lane & 15;
    const int wr   = w >> 1, wc = w & 1;
    const int m0   = blockIdx.y * 64;
    const int n0   = blockIdx.x * 64;
    const int K    = DMODEL;

    f32x4 acc[2][2] = {};

    for (int k0 = 0; k0 < K; k0 += 64) {
        __syncthreads();
        // 1024 chunks (A:512, B:512); 4 wave-uniform calls/wave
        #pragma unroll
        for (int j = 0; j < 4; ++j) {
            const int base = w * 256 + j * 64;   // w<2 -> A, w>=2 -> B (uniform)
            const int c = base + lane;
            if (base < 512) {
                const int row = c >> 3, pos = (c & 7) ^ (row & 7);
                async_ld16(Ahi + (size_t)(m0 + row) * K + k0 + pos * 8, Ah + base * 8);
            } else {
                const int cb = c - 512;
                const int row = cb >> 3, pos = (cb & 7) ^ (row & 7);
                async_ld16(Bthi + (size_t)(n0 + row) * K + k0 + pos * 8, Bh + (base - 512) * 8);
            }
        }
        __syncthreads();

        #pragma unroll
        for (int s = 0; s < 2; ++s) {
            bf16x8 afh[2], bfh[2];
            #pragma unroll
            for (int mi = 0; mi < 2; ++mi) {
                const int row = wr * 32 + mi * 16 + l15;
                const int pos = (s * 4 + quad) ^ (row & 7);
                afh[mi] = *(const bf16x8*)(Ah + row * 64 + pos * 8);
            }
            #pragma unroll
            for (int ni = 0; ni < 2; ++ni) {
                const int row = wc * 32 + ni * 16 + l15;
                const int pos = (s * 4 + quad) ^ (row & 7);
                bfh[ni] = *(const bf16x8*)(Bh + row * 64 + pos * 8);
            }
            #pragma unroll
            for (int mi = 0; mi < 2; ++mi)
                #pragma unroll
                for (int ni = 0; ni < 2; ++ni)
                    acc[mi][ni] = __builtin_amdgcn_mfma_f32_16x16x32_bf16(
                        afh[mi], bfh[ni], acc[mi][ni], 0, 0, 0);
        }
    }

    #pragma unroll
    for (int mi = 0; mi < 2; ++mi)
        #pragma unroll
        for (int ni = 0; ni < 2; ++ni)
            #pragma unroll
            for (int r = 0; r < 4; ++r) {
                const int m = m0 + wr * 32 + mi * 16 + quad * 4 + r;
                const int nn = n0 + wc * 32 + ni * 16 + l15;
                outf[(size_t)m * DMODEL + nn] = acc[mi][ni][r] + b0[nn];
            }
}

// ---------------- MFMA flash attention v12: split-K x4, 24 KB LDS ----------------
// Shared per-wave Ph tile: PV for q-frag A then B sequentially (wave-private
// in-order DS ops); B's packed P parked in VGPRs during PV_A.
__global__ __launch_bounds__(256) void attn_mfma(
    const short* __restrict__ Qh_g, const short* __restrict__ Kh_g,
    const short* __restrict__ Vth_g,
    short* __restrict__ op0, float* __restrict__ l0g)
{
    __shared__ short Ksh[4096];          // [key][d] swizzled, 8 KB
    __shared__ short Vsh[4096];          // [d][s] swizzled, 8 KB
    __shared__ short Ph[4][1024];        // [wave][16x64 swizzled], 8 KB

    const int tid  = threadIdx.x;
    const int lane = tid & 63;
    const int w    = tid >> 6;
    const int quad = lane >> 4;
    const int l15  = lane & 15;

    const int bh    = blockIdx.x & 31;        // XCD-local head
    const int sk    = (blockIdx.x >> 5) & 3;  // K-split quarter
    const int qtile = blockIdx.x >> 7;        // 0..15
    const int q0    = qtile * 128 + w * 32;
    const size_t kvb = (size_t)bh * SEQ * DHEAD;

    bf16x8 ones;
    #pragma unroll
    for (int j = 0; j < 8; ++j) ones[j] = (short)0x3f80;   // bf16 1.0

    bf16x8 qA[2], qB[2];
    {
        const size_t qrA = kvb + (size_t)(q0 + l15) * DHEAD;
        const size_t qrB = kvb + (size_t)(q0 + 16 + l15) * DHEAD;
        qA[0] = *(const bf16x8*)(Qh_g + qrA + quad * 8);
        qA[1] = *(const bf16x8*)(Qh_g + qrA + 32 + quad * 8);
        qB[0] = *(const bf16x8*)(Qh_g + qrB + quad * 8);
        qB[1] = *(const bf16x8*)(Qh_g + qrB + 32 + quad * 8);
    }

    const bool isv = (w >= 2);
    short* dst = isv ? Vsh : Ksh;
    int srow[4], spos[4];
    #pragma unroll
    for (int j = 0; j < 4; ++j) {
        const int c = (w & 1) * 256 + j * 64 + lane;
        srow[j] = c >> 3;
        spos[j] = (c & 7) ^ (srow[j] & 7);
    }

    f32x4 oA[4] = {}, oB[4] = {};
    f32x4 lAv = {}, lBv = {};

    const int kb0 = sk * (SEQ / 4), kb1 = kb0 + SEQ / 4;   // 8 iters
    for (int kb = kb0; kb < kb1; kb += 64) {
        __syncthreads();
        {
            const short* src = isv ? (Vth_g + kvb + kb) : (Kh_g + kvb + (size_t)kb * DHEAD);
            #pragma unroll
            for (int j = 0; j < 4; ++j) {
                const short* g = src + (isv ? ((size_t)srow[j] * SEQ + spos[j] * 8)
                                            : ((size_t)srow[j] * DHEAD + spos[j] * 8));
                async_ld16(g, dst + ((w & 1) * 256 + j * 64) * 8);
            }
        }
        __syncthreads();

        // ---- S^T = K Q^T for both q-fragments (K frags read once) ----
        uint2 pkB[4];   // parked packed P for frag B
        #pragma unroll
        for (int mf = 0; mf < 4; ++mf) {
            const int row = mf * 16 + l15;
            const int sw = row & 7;
            bf16x8 kh0 = *(const bf16x8*)(Ksh + row * 64 + ((quad ^ sw) * 8));
            bf16x8 kh1 = *(const bf16x8*)(Ksh + row * 64 + (((4 + quad) ^ sw) * 8));
            f32x4 cA = {}, cB = {};
            cA = __builtin_amdgcn_mfma_f32_16x16x32_bf16(kh0, qA[0], cA, 0, 0, 0);
            cA = __builtin_amdgcn_mfma_f32_16x16x32_bf16(kh1, qA[1], cA, 0, 0, 0);
            cB = __builtin_amdgcn_mfma_f32_16x16x32_bf16(kh0, qB[0], cB, 0, 0, 0);
            cB = __builtin_amdgcn_mfma_f32_16x16x32_bf16(kh1, qB[1], cB, 0, 0, 0);

            unsigned uA[4], uB[4];
            #pragma unroll
            for (int r = 0; r < 4; ++r) {
                union { float f; unsigned u; } p;
                p.f = __builtin_amdgcn_exp2f(cA[r]);
                uA[r] = p.u;
                p.f = __builtin_amdgcn_exp2f(cB[r]);
                uB[r] = p.u;
            }
            uint2 pkA;
            pkA.x = __builtin_amdgcn_perm(uA[1], uA[0], 0x07060302u);
            pkA.y = __builtin_amdgcn_perm(uA[3], uA[2], 0x07060302u);
            pkB[mf].x = __builtin_amdgcn_perm(uB[1], uB[0], 0x07060302u);
            pkB[mf].y = __builtin_amdgcn_perm(uB[3], uB[2], 0x07060302u);
            const int pc = (mf * 2 + (quad >> 1)) ^ (l15 & 7);
            const int paddr = l15 * 64 + pc * 8 + (quad & 1) * 4;
            *(uint2*)(&Ph[w][paddr]) = pkA;
        }
        // wave-private LDS: in-order within wave, no barrier needed

        const int psw = l15 & 7;
        bf16x8 pA0 = *(const bf16x8*)(&Ph[w][l15 * 64 + ((quad ^ psw) * 8)]);
        bf16x8 pA1 = *(const bf16x8*)(&Ph[w][l15 * 64 + (((4 + quad) ^ psw) * 8)]);

        lAv = __builtin_amdgcn_mfma_f32_16x16x32_bf16(pA0, ones, lAv, 0, 0, 0);
        lAv = __builtin_amdgcn_mfma_f32_16x16x32_bf16(pA1, ones, lAv, 0, 0, 0);
        #pragma unroll
        for (int nf = 0; nf < 4; ++nf) {
            const int row = nf * 16 + l15;
            const int sw = row & 7;
            bf16x8 vh0 = *(const bf16x8*)(Vsh + row * 64 + ((quad ^ sw) * 8));
            bf16x8 vh1 = *(const bf16x8*)(Vsh + row * 64 + (((4 + quad) ^ sw) * 8));
            f32x4 cA = oA[nf];
            cA = __builtin_amdgcn_mfma_f32_16x16x32_bf16(pA0, vh0, cA, 0, 0, 0);
            cA = __builtin_amdgcn_mfma_f32_16x16x32_bf16(pA1, vh1, cA, 0, 0, 0);
            oA[nf] = cA;
        }

        // ---- frag B through the same Ph (in-order DS: writes follow reads) ----
        #pragma unroll
        for (int mf = 0; mf < 4; ++mf) {
            const int pc = (mf * 2 + (quad >> 1)) ^ (l15 & 7);
            const int paddr = l15 * 64 + pc * 8 + (quad & 1) * 4;
            *(uint2*)(&Ph[w][paddr]) = pkB[mf];
        }
        bf16x8 pB0 = *(const bf16x8*)(&Ph[w][l15 * 64 + ((quad ^ psw) * 8)]);
        bf16x8 pB1 = *(const bf16x8*)(&Ph[w][l15 * 64 + (((4 + quad) ^ psw) * 8)]);

        lBv = __builtin_amdgcn_mfma_f32_16x16x32_bf16(pB0, ones, lBv, 0, 0, 0);
        lBv = __builtin_amdgcn_mfma_f32_16x16x32_bf16(pB1, ones, lBv, 0, 0, 0);
        #pragma unroll
        for (int nf = 0; nf < 4; ++nf) {
            const int row = nf * 16 + l15;
            const int sw = row & 7;
            bf16x8 vh0 = *(const bf16x8*)(Vsh + row * 64 + ((quad ^ sw) * 8));
            bf16x8 vh1 = *(const bf16x8*)(Vsh + row * 64 + (((4 + quad) ^ sw) * 8));
            f32x4 cB = oB[nf];
            cB = __builtin_amdgcn_mfma_f32_16x16x32_bf16(pB0, vh0, cB, 0, 0, 0);
            cB = __builtin_amdgcn_mfma_f32_16x16x32_bf16(pB1, vh1, cB, 0, 0, 0);
            oB[nf] = cB;
        }
    }

    // ---- epilogue: bf16 unnormalized partial O + fp32 partial l ----
    short* op = op0 + (size_t)sk * 4194304;       // partials 8 MB apart
    float* lg = l0g + sk * 65536;
    const int b = bh >> 4, hh = bh & 15;
    #pragma unroll
    for (int r = 0; r < 4; ++r) {
        const int qa = q0 + quad * 4 + r;
        if (l15 == 0) {
            lg[bh * SEQ + qa] = lAv[r];
            lg[bh * SEQ + qa + 16] = lBv[r];
        }
    }
    #pragma unroll
    for (int nf = 0; nf < 4; ++nf) {
        #pragma unroll
        for (int r = 0; r < 4; ++r) {
            const int qa = q0 + quad * 4 + r;
            const int d = nf * 16 + l15;
            op[(size_t)(b * SEQ + qa) * DMODEL + hh * DHEAD + d] = f2bf(oA[nf][r]);
            op[(size_t)(b * SEQ + qa + 16) * DMODEL + hh * DHEAD + d] = f2bf(oB[nf][r]);
        }
    }
}

// ---------------- combine: aoh = bf16(sum4(O)/sum4(l)), bf16 inputs ----------------
__global__ __launch_bounds__(256) void combine_o(
    const short* __restrict__ op0, const float* __restrict__ l0g,
    short* __restrict__ aoh)
{
    const int i = blockIdx.x * 256 + threadIdx.x;   // 8 elems each; grid 2048
    const size_t e = (size_t)i * 8;
    const int qg = (int)(e >> 10);
    const int col = (int)(e & 1023);
    const int b = qg >> 11;
    const int q = qg & (SEQ - 1);
    const int bhq = (b * NHEADS + (col >> 6)) * SEQ + q;
    const float inv = 1.0f / (l0g[bhq] + l0g[bhq + 65536] +
                              l0g[bhq + 2 * 65536] + l0g[bhq + 3 * 65536]);

    bf16x8 a0 = *((const bf16x8*)op0 + i);
    bf16x8 a1 = *((const bf16x8*)(op0 + 4194304) + i);
    bf16x8 a2 = *((const bf16x8*)(op0 + 2 * 4194304) + i);
    bf16x8 a3 = *((const bf16x8*)(op0 + 3 * 4194304) + i);
    bf16x8 H;
    #pragma unroll
    for (int j = 0; j < 8; ++j)
        H[j] = f2bf((bf2f(a0[j]) + bf2f(a1[j]) + bf2f(a2[j]) + bf2f(a3[j])) * inv);
    *((bf16x8*)aoh + i) = H;
}

// ---------------- launch ----------------
extern "C" void kernel_launch(void* const* d_in, const int* in_sizes, int n_in,
                              void* d_out, int out_size, void* d_ws, size_t ws_size,
                              hipStream_t stream) {
    const float* x  = (const float*)d_in[0];
    // d_in[1] = pH : softmax shift-invariant, ignored
    const float* Wq = (const float*)d_in[2];
    const float* bq = (const float*)d_in[3];
    const float* Wk = (const float*)d_in[4];
    const float* bk = (const float*)d_in[5];
    const float* Wv = (const float*)d_in[6];
    const float* bv = (const float*)d_in[7];
    const float* Wo = (const float*)d_in[8];
    const float* bo = (const float*)d_in[9];
    float* out = (float*)d_out;

    char* ws = (char*)d_ws;
    const size_t MB = 1024 * 1024;
    short* qh  = (short*)(ws + 0 * MB);      // 8 MB
    short* kh  = (short*)(ws + 16 * MB);     // 8 MB
    short* vth = (short*)(ws + 32 * MB);     // 8 MB
    short* aoh = (short*)(ws + 48 * MB);     // 8 MB
    short* op0 = (short*)(ws + 56 * MB);     // 4x8 MB bf16 partials at 56/64/72/80
    short* xhi = (short*)(ws + 64 * MB);     // 8 MB (dead after QKV GEMM)
    short* wqkv_hi = (short*)(ws + 80 * MB); // 6 MB (dead after QKV GEMM)
    float* l0g = (float*)(ws + 88 * MB);     // 4x256 KB partial l
    short* wto_hi  = (short*)(ws + 92 * MB); // 2 MB

    dim3 blk(256);

    hipLaunchKernelGGL(prep, dim3(2048 + 1024), blk, 0, stream,
                       x, xhi, Wq, Wk, Wv, Wo, wqkv_hi, wto_hi);

    const float qscale = 0.125f * 1.44269504088896f;   // fold 1/sqrt(dh)*log2(e)
    hipLaunchKernelGGL(qkv_gemm, dim3(3072 / 128, MROWS / 64), blk, 0, stream,
                       xhi, wqkv_hi, bq, bk, bv, qh, kh, vth, qscale);

    hipLaunchKernelGGL(attn_mfma, dim3(BATCH * NHEADS * (SEQ / 128) * 4), blk, 0, stream,
                       qh, kh, vth, op0, l0g);

    hipLaunchKernelGGL(combine_o, dim3(MROWS * DMODEL / 8 / 256), blk, 0, stream,
                       op0, l0g, aoh);

    hipLaunchKernelGGL(ogemm, dim3(1024 / 64, MROWS / 64), blk, 0, stream,
                       aoh, wto_hi, bo, out);
}